// Round 11
// baseline (2941.765 us; speedup 1.0000x reference)
//
#include <hip/hip_runtime.h>
#include <cstdint>
#include <cstddef>

#define DEV_INLINE __device__ __forceinline__

typedef __attribute__((ext_vector_type(8))) short bf16x8;
typedef __attribute__((ext_vector_type(16))) float f32x16;
struct __align__(8) US4 { unsigned short u[4]; };

DEV_INLINE unsigned short f2bf(float x) {
  unsigned u = __float_as_uint(x);
  return (unsigned short)((u + 0x7FFFu + ((u >> 16) & 1u)) >> 16);
}
DEV_INLINE float bf2f(unsigned short u) { return __uint_as_float(((unsigned)u) << 16); }
DEV_INLINE float2 bfpair(unsigned v) {
  return make_float2(__uint_as_float(v << 16), __uint_as_float(v & 0xFFFF0000u));
}
DEV_INLINE float ftanh(float x) {
  float e = __expf(2.0f * x);
  return 1.0f - 2.0f / (e + 1.0f);
}
DEV_INLINE float softplus_neg(float x) {
  return (x >= 0.f) ? log1pf(__expf(-x)) : (-x + log1pf(__expf(x)));
}

// ---------------------------------------------------------------------------
// Grid barrier for persistent kernels (device-scope atomics; cross-XCD safe)
// ---------------------------------------------------------------------------
DEV_INLINE void grid_barrier(unsigned* cnt, unsigned* gen, int nblk) {
  __threadfence();
  __syncthreads();
  if (threadIdx.x == 0) {
    unsigned g = __hip_atomic_load(gen, __ATOMIC_RELAXED, __HIP_MEMORY_SCOPE_AGENT);
    if (__hip_atomic_fetch_add(cnt, 1u, __ATOMIC_ACQ_REL, __HIP_MEMORY_SCOPE_AGENT)
        == (unsigned)(nblk - 1)) {
      __hip_atomic_store(cnt, 0u, __ATOMIC_RELAXED, __HIP_MEMORY_SCOPE_AGENT);
      __hip_atomic_fetch_add(gen, 1u, __ATOMIC_ACQ_REL, __HIP_MEMORY_SCOPE_AGENT);
    } else {
      while (__hip_atomic_load(gen, __ATOMIC_RELAXED, __HIP_MEMORY_SCOPE_AGENT) == g) {
        __builtin_amdgcn_s_sleep(2);
      }
    }
  }
  __syncthreads();
  __threadfence();
}

// ---------------------------------------------------------------------------
// Batched f32 -> bf16 conversion (+ zeroes the grid-barrier counter)
// ---------------------------------------------------------------------------
struct CvtSeg { const float* src; unsigned short* dst; int n; int nblk; };
struct CvtArgs { CvtSeg seg[16]; int nseg; };

__global__ __launch_bounds__(256) void convert_bf16_many(CvtArgs args, unsigned* cnt) {
  if (blockIdx.x == 0 && threadIdx.x == 0) *cnt = 0;
  int b = blockIdx.x;
  int s = 0;
  while (s < args.nseg && b >= args.seg[s].nblk) { b -= args.seg[s].nblk; ++s; }
  if (s >= args.nseg) return;
  int base = b * 1024 + threadIdx.x * 4;
  if (base >= args.seg[s].n) return;
  float4 v = *reinterpret_cast<const float4*>(args.seg[s].src + base);
  US4 o;
  o.u[0] = f2bf(v.x); o.u[1] = f2bf(v.y); o.u[2] = f2bf(v.z); o.u[3] = f2bf(v.w);
  *reinterpret_cast<US4*>(args.seg[s].dst + base) = o;
}

// ---------------------------------------------------------------------------
// bf16 MFMA GEMM: C = X @ W^T + bias; per-seg f32 (C) or bf16 (Cb) output.
// ---------------------------------------------------------------------------
struct GSeg { const unsigned short* X; const unsigned short* W; const float* bias;
              float* C; unsigned short* Cb; int N; int O; int blk0; int xblk; };
struct GSegs { GSeg s[8]; int nseg; };

__global__ __launch_bounds__(256) void gemm_bf16_gseg(GSegs gs) {
  __shared__ __align__(16) unsigned short Xs[128 * 128];
  __shared__ __align__(16) unsigned short Ws[64 * 128];
  int bx = blockIdx.x;
  int si = 0;
  while (si + 1 < gs.nseg && bx >= gs.s[si + 1].blk0) ++si;
  const GSeg& g = gs.s[si];
  int b = bx - g.blk0;
  int bm = (b % g.xblk) * 128;
  int bn = (b / g.xblk) * 64;
  const int tid = threadIdx.x;

#pragma unroll
  for (int i = 0; i < 8; ++i) {
    int s = tid + 256 * i;
    int row = s >> 4, c16 = s & 15;
    uint4 v = make_uint4(0, 0, 0, 0);
    int gr = bm + row;
    if (gr < g.N) v = *reinterpret_cast<const uint4*>(g.X + (size_t)gr * 128 + c16 * 8);
    *reinterpret_cast<uint4*>(&Xs[(row * 16 + (c16 ^ (row & 7))) * 8]) = v;
  }
#pragma unroll
  for (int i = 0; i < 4; ++i) {
    int s = tid + 256 * i;
    int row = s >> 4, c16 = s & 15;
    uint4 v = make_uint4(0, 0, 0, 0);
    int gw = bn + row;
    if (gw < g.O) v = *reinterpret_cast<const uint4*>(g.W + (size_t)gw * 128 + c16 * 8);
    *reinterpret_cast<uint4*>(&Ws[(row * 16 + (c16 ^ (row & 7))) * 8]) = v;
  }
  __syncthreads();

  const int wave = tid >> 6, lane = tid & 63;
  const int l31 = lane & 31, lhi = lane >> 5;

  f32x16 acc0, acc1;
#pragma unroll
  for (int i = 0; i < 16; ++i) { acc0[i] = 0.f; acc1[i] = 0.f; }
  const int ar = wave * 32 + l31;
#pragma unroll
  for (int ks = 0; ks < 8; ++ks) {
    int c16 = ks * 2 + lhi;
    bf16x8 a  = *reinterpret_cast<const bf16x8*>(&Xs[(ar * 16 + (c16 ^ (ar & 7))) * 8]);
    bf16x8 b0 = *reinterpret_cast<const bf16x8*>(&Ws[(l31 * 16 + (c16 ^ (l31 & 7))) * 8]);
    int br1 = 32 + l31;
    bf16x8 b1 = *reinterpret_cast<const bf16x8*>(&Ws[(br1 * 16 + (c16 ^ (br1 & 7))) * 8]);
    acc0 = __builtin_amdgcn_mfma_f32_32x32x16_bf16(a, b0, acc0, 0, 0, 0);
    acc1 = __builtin_amdgcn_mfma_f32_32x32x16_bf16(a, b1, acc1, 0, 0, 0);
  }

  if (g.Cb) {
#pragma unroll
    for (int reg = 0; reg < 16; ++reg) {
      int r = bm + wave * 32 + (reg & 3) + 8 * (reg >> 2) + 4 * lhi;
      if (r < g.N) {
        int c0 = bn + l31;
        if (c0 < g.O) g.Cb[(size_t)r * g.O + c0] = f2bf(acc0[reg] + g.bias[c0]);
        int c1 = bn + 32 + l31;
        if (c1 < g.O) g.Cb[(size_t)r * g.O + c1] = f2bf(acc1[reg] + g.bias[c1]);
      }
    }
  } else {
#pragma unroll
    for (int reg = 0; reg < 16; ++reg) {
      int r = bm + wave * 32 + (reg & 3) + 8 * (reg >> 2) + 4 * lhi;
      if (r < g.N) {
        int c0 = bn + l31;
        if (c0 < g.O) g.C[(size_t)r * g.O + c0] = acc0[reg] + g.bias[c0];
        int c1 = bn + 32 + l31;
        if (c1 < g.O) g.C[(size_t)r * g.O + c1] = acc1[reg] + g.bias[c1];
      }
    }
  }
}

// ---------------------------------------------------------------------------
// Phase bodies (used by persistent stage kernel)
// ---------------------------------------------------------------------------
// rowops: softmax/CE/tcp from bf16 logits (750 bf16-pairs / row)
DEV_INLINE void rowops_body_b(int lane, const unsigned* __restrict__ lrb,
                              const float2* __restrict__ cr2,
                              const float* __restrict__ srcrow,
                              float* __restrict__ scaledrow, float* __restrict__ cep)
{
  float2 e[12];
  float m = -3.4e38f;
#pragma unroll
  for (int k = 0; k < 12; ++k) {
    int idx = k * 64 + lane;
    if (idx < 750) {
      e[k] = bfpair(lrb[idx]);
      m = fmaxf(m, fmaxf(e[k].x, e[k].y));
    } else {
      e[k] = make_float2(-3.4e38f, -3.4e38f);
    }
  }
#pragma unroll
  for (int o = 1; o < 64; o <<= 1) m = fmaxf(m, __shfl_xor(m, o));
  float z = 0.f;
#pragma unroll
  for (int k = 0; k < 12; ++k) {
    e[k].x = __expf(e[k].x - m); e[k].y = __expf(e[k].y - m);
    z += e[k].x + e[k].y;
  }
#pragma unroll
  for (int o = 1; o < 64; o <<= 1) z += __shfl_xor(z, o);
  float invZ1 = 1.0f / z;
  float m2 = invZ1;
  float t = 0.f, ls = 0.f, z2 = 0.f;
#pragma unroll
  for (int k = 0; k < 12; ++k) {
    int idx = k * 64 + lane;
    if (idx < 750) {
      float2 c = cr2[idx];
      float px = e[k].x * invZ1, py = e[k].y * invZ1;
      t  += c.x * px + c.y * py;
      ls += c.x + c.y;
      z2 += __expf(px - m2) + __expf(py - m2);
    }
  }
#pragma unroll
  for (int o = 1; o < 64; o <<= 1) {
    t += __shfl_xor(t, o); ls += __shfl_xor(ls, o); z2 += __shfl_xor(z2, o);
  }
  if (lane == 0) *cep = t - ls * (m2 + logf(z2));
  scaledrow[lane]      = t * srcrow[lane];
  scaledrow[lane + 64] = t * srcrow[lane + 64];
}

// spmv: ballot-scan one row per block (4 waves), bf16 output only
DEV_INLINE void spmv_body_b(const float* __restrict__ A, const float* __restrict__ Xs,
                            unsigned short* __restrict__ Hb, int row, int K,
                            float (*red)[128])
{
  int tid = threadIdx.x, wave = tid >> 6, lane = tid & 63;
  const float4* Arow = reinterpret_cast<const float4*>(A + (size_t)row * K);
  int K4 = K >> 2;
  float acc0 = 0.f, acc1 = 0.f;
  int base = wave * 64;
  int q = base + lane;
  float4 a = (base < K4 && q < K4) ? Arow[q] : make_float4(0.f, 0.f, 0.f, 0.f);
  for (; base < K4; base += 256) {
    int nb = base + 256;
    int nq = nb + lane;
    float4 an = (nb < K4 && nq < K4) ? Arow[nq] : make_float4(0.f, 0.f, 0.f, 0.f);
#pragma unroll
    for (int c = 0; c < 4; ++c) {
      float av = (c == 0) ? a.x : (c == 1) ? a.y : (c == 2) ? a.z : a.w;
      unsigned long long mm = __ballot(av != 0.f);
      while (mm) {
        int b = __builtin_ctzll(mm);
        mm &= mm - 1;
        float v = __shfl(av, b);
        int jj = (base + b) * 4 + c;
        const float* xr = Xs + (size_t)jj * 128;
        acc0 += v * xr[lane];
        acc1 += v * xr[lane + 64];
      }
    }
    a = an;
  }
  red[wave][lane] = acc0;
  red[wave][lane + 64] = acc1;
  __syncthreads();
  if (wave == 0) {
    float r0 = red[0][lane] + red[1][lane] + red[2][lane] + red[3][lane];
    float r1 = red[0][lane + 64] + red[1][lane + 64] + red[2][lane + 64] + red[3][lane + 64];
    Hb[(size_t)row * 128 + lane] = f2bf(r0);
    Hb[(size_t)row * 128 + 64 + lane] = f2bf(r1);
  }
  __syncthreads();
}

// gh-GEMM + GRU: 32-row tile; bf16 H / gi
struct GrSeg { const unsigned short* whh; const float* bhh; const unsigned short* gi;
               const unsigned short* hb; float* out; unsigned short* outb; int m; };

DEV_INLINE void ghgru_body_b(const GrSeg& g, int bm, unsigned short* As)
{
  const int tid = threadIdx.x;
#pragma unroll
  for (int i = 0; i < 2; ++i) {
    int s = tid + 256 * i;
    int row = s >> 4, c16 = s & 15;
    uint4 v = make_uint4(0, 0, 0, 0);
    int gr = bm + row;
    if (gr < g.m) v = *reinterpret_cast<const uint4*>(g.hb + (size_t)gr * 128 + c16 * 8);
    *reinterpret_cast<uint4*>(&As[(row * 16 + (c16 ^ (row & 7))) * 8]) = v;
  }
  __syncthreads();

  const int wave = tid >> 6, lane = tid & 63;
  const int l31 = lane & 31, lhi = lane >> 5;
  const int d = wave * 32 + l31;

  f32x16 ar, az, an;
#pragma unroll
  for (int i = 0; i < 16; ++i) { ar[i] = 0.f; az[i] = 0.f; an[i] = 0.f; }

#pragma unroll
  for (int ks = 0; ks < 8; ++ks) {
    int c16 = ks * 2 + lhi;
    bf16x8 a = *reinterpret_cast<const bf16x8*>(&As[(l31 * 16 + (c16 ^ (l31 & 7))) * 8]);
    const unsigned short* wb = g.whh + (size_t)c16 * 8;
    bf16x8 br = *reinterpret_cast<const bf16x8*>(wb + (size_t)d * 128);
    bf16x8 bz = *reinterpret_cast<const bf16x8*>(wb + (size_t)(128 + d) * 128);
    bf16x8 bn = *reinterpret_cast<const bf16x8*>(wb + (size_t)(256 + d) * 128);
    ar = __builtin_amdgcn_mfma_f32_32x32x16_bf16(a, br, ar, 0, 0, 0);
    az = __builtin_amdgcn_mfma_f32_32x32x16_bf16(a, bz, az, 0, 0, 0);
    an = __builtin_amdgcn_mfma_f32_32x32x16_bf16(a, bn, an, 0, 0, 0);
  }

  const float b_r = g.bhh[d], b_z = g.bhh[128 + d], b_n = g.bhh[256 + d];
#pragma unroll
  for (int reg = 0; reg < 16; ++reg) {
    int rowl = (reg & 3) + 8 * (reg >> 2) + 4 * lhi;
    int r = bm + rowl;
    if (r < g.m) {
      const unsigned short* gir = g.gi + (size_t)r * 384;
      float rr = 1.f / (1.f + __expf(-(bf2f(gir[d]) + ar[reg] + b_r)));
      float zz = 1.f / (1.f + __expf(-(bf2f(gir[128 + d]) + az[reg] + b_z)));
      float nn = ftanh(bf2f(gir[256 + d]) + rr * (an[reg] + b_n));
      float h = bf2f(As[(rowl * 16 + ((d >> 3) ^ (rowl & 7))) * 8 + (d & 7)]);
      float o = (1.f - zz) * nn + zz * h;
      g.out[(size_t)r * 128 + d] = o;
      g.outb[(size_t)r * 128 + d] = f2bf(o);
    }
  }
  __syncthreads();
}

// ---------------------------------------------------------------------------
// Persistent stage kernel: rowops -> barrier -> spmv -> barrier -> gru
// ---------------------------------------------------------------------------
struct RoSeg { const unsigned* lg; const float* cls; const float* src; float* sc; float* ce; int n; };
struct SpSeg { const float* adj; const float* x; unsigned short* hb; int m; int k; };
struct StageArgs {
  RoSeg r0, r1; SpSeg s0, s1; GrSeg g0, g1; int two;
  unsigned* cnt; unsigned* gen; int nblk;
};

__global__ __launch_bounds__(256, 4) void stage_kernel(StageArgs a) {
  __shared__ __align__(16) unsigned char smem[8192];
  const int lane = threadIdx.x & 63;
  // phase 1: rowops (wave per row)
  {
    int nro = a.r0.n + (a.two ? a.r1.n : 0);
    int wslot = blockIdx.x * 4 + (threadIdx.x >> 6);
    for (int gw = wslot; gw < nro; gw += a.nblk * 4) {
      const RoSeg& rs = (gw < a.r0.n) ? a.r0 : a.r1;
      int r = (gw < a.r0.n) ? gw : gw - a.r0.n;
      rowops_body_b(lane, rs.lg + (size_t)r * 750,
                    reinterpret_cast<const float2*>(rs.cls + (size_t)r * 1500),
                    rs.src + (size_t)r * 128, rs.sc + (size_t)r * 128, rs.ce + r);
    }
  }
  grid_barrier(a.cnt, a.gen, a.nblk);
  // phase 2: spmv (block per row)
  {
    float (*red)[128] = reinterpret_cast<float (*)[128]>(smem);
    int nsp = a.s0.m + (a.two ? a.s1.m : 0);
    for (int row = blockIdx.x; row < nsp; row += a.nblk) {
      const SpSeg& ss = (row < a.s0.m) ? a.s0 : a.s1;
      int r = (row < a.s0.m) ? row : row - a.s0.m;
      spmv_body_b(ss.adj, ss.x, ss.hb, r, ss.k, red);
    }
  }
  grid_barrier(a.cnt, a.gen, a.nblk);
  // phase 3: gru (block per 32-row tile)
  {
    unsigned short* As = reinterpret_cast<unsigned short*>(smem);
    int t0 = (a.g0.m + 31) >> 5;
    int t1 = a.two ? ((a.g1.m + 31) >> 5) : 0;
    for (int t = blockIdx.x; t < t0 + t1; t += a.nblk) {
      const GrSeg& gg = (t < t0) ? a.g0 : a.g1;
      int tt = (t < t0) ? t : t - t0;
      ghgru_body_b(gg, tt * 32, As);
    }
  }
}

// ---------------------------------------------------------------------------
// Persistent tail kernel: scores -> denom -> emb -> edges -> final
// ---------------------------------------------------------------------------
struct TailArgs {
  const float* e0; const float* e1;
  const float* W2; const float* b2; const float* W3; const float* b3;
  float* sc0; float* sc1; float* den;
  const float* rel; float* fe; unsigned short* feb; float* rel_out;
  const int* ud; const int* us; const unsigned short* relb;
  float* partial; const float* cebuf; float* outp;
  unsigned* cnt; unsigned* gen; int nblk;
};

__global__ __launch_bounds__(256, 4) void tail_kernel(TailArgs a) {
  __shared__ float tsm[256];
  __shared__ float red8[8];
  const int tid = threadIdx.x;
  const int lane = tid & 63;
  // phase A: fuse scores (wave per row)
  {
    int wslot = blockIdx.x * 4 + (tid >> 6);
    for (int row = wslot; row < 18500; row += a.nblk * 4) {
      float v0 = a.e0[(size_t)row * 128 + lane] * a.W2[lane]
               + a.e0[(size_t)row * 128 + 64 + lane] * a.W2[64 + lane];
      float v1 = a.e1[(size_t)row * 128 + lane] * a.W3[lane]
               + a.e1[(size_t)row * 128 + 64 + lane] * a.W3[64 + lane];
#pragma unroll
      for (int o = 32; o > 0; o >>= 1) { v0 += __shfl_down(v0, o); v1 += __shfl_down(v1, o); }
      if (lane == 0) {
        a.sc0[row] = fmaxf(v0 + a.b2[0], 0.f);
        a.sc1[row] = fmaxf(v1 + a.b3[0], 0.f);
      }
    }
  }
  grid_barrier(a.cnt, a.gen, a.nblk);
  // phase B: denom (blocks 0..3, one entity each)
  if (blockIdx.x < 4) {
    const int ns_[4]  = {8000, 3000, 1500, 6000};
    const int offs[4] = {0, 8000, 11000, 12500};
    int b = blockIdx.x;
    int n = ns_[b];
    const float* p0 = a.sc0 + offs[b];
    const float* p1 = a.sc1 + offs[b];
    float m = -3.4e38f;
    for (int i = tid; i < n; i += 256) m = fmaxf(m, p0[i]);
    tsm[tid] = m; __syncthreads();
    for (int s = 128; s > 0; s >>= 1) { if (tid < s) tsm[tid] = fmaxf(tsm[tid], tsm[tid + s]); __syncthreads(); }
    float m0 = tsm[0]; __syncthreads();
    float z = 0.f;
    for (int i = tid; i < n; i += 256) z += __expf(p0[i] - m0);
    tsm[tid] = z; __syncthreads();
    for (int s = 128; s > 0; s >>= 1) { if (tid < s) tsm[tid] += tsm[tid + s]; __syncthreads(); }
    float Z0 = tsm[0]; __syncthreads();
    m = -3.4e38f;
    for (int i = tid; i < n; i += 256) m = fmaxf(m, p1[i]);
    tsm[tid] = m; __syncthreads();
    for (int s = 128; s > 0; s >>= 1) { if (tid < s) tsm[tid] = fmaxf(tsm[tid], tsm[tid + s]); __syncthreads(); }
    float m1 = tsm[0]; __syncthreads();
    z = 0.f;
    for (int i = tid; i < n; i += 256) z += __expf(p1[i] - m1);
    tsm[tid] = z; __syncthreads();
    for (int s = 128; s > 0; s >>= 1) { if (tid < s) tsm[tid] += tsm[tid + s]; __syncthreads(); }
    if (tid == 0) {
      a.den[b * 4] = m0; a.den[b * 4 + 1] = Z0;
      a.den[b * 4 + 2] = m1; a.den[b * 4 + 3] = tsm[0];
    }
  }
  grid_barrier(a.cnt, a.gen, a.nblk);
  // phase C: fuse emb (+rel copy), 2 elems/thread
  {
    const int tot2 = 18500 * 64;
    for (int t = blockIdx.x * 256 + tid; t < tot2 + 768; t += a.nblk * 256) {
      if (t < tot2) {
        int idx = t * 2;
        int row = idx >> 7;
        int e = (row < 8000) ? 0 : (row < 11000) ? 1 : (row < 12500) ? 2 : 3;
        float a0 = __expf(a.sc0[row] - a.den[e * 4]) / a.den[e * 4 + 1];
        float a1 = __expf(a.sc1[row] - a.den[e * 4 + 2]) / a.den[e * 4 + 3];
        float2 v0 = *reinterpret_cast<const float2*>(a.e0 + idx);
        float2 v1 = *reinterpret_cast<const float2*>(a.e1 + idx);
        float r0 = fmaxf(a0 * v0.x + a1 * v1.x, 0.f);
        float r1 = fmaxf(a0 * v0.y + a1 * v1.y, 0.f);
        *reinterpret_cast<float2*>(a.fe + idx) = make_float2(r0, r1);
        unsigned pb = (unsigned)f2bf(r0) | ((unsigned)f2bf(r1) << 16);
        *reinterpret_cast<unsigned*>(a.feb + idx) = pb;
      } else {
        int k = (t - tot2) * 2;
        *reinterpret_cast<float2*>(a.rel_out + k) = *reinterpret_cast<const float2*>(a.rel + k);
      }
    }
  }
  grid_barrier(a.cnt, a.gen, a.nblk);
  // phase D: edges (half-wave per edge, fast tanh, prefetch)
  {
    const int l = lane & 31, h = lane >> 5;
    const int wid = tid >> 6;
    const int half = a.nblk >> 1;
    bool is_d = ((int)blockIdx.x < half);
    int bb = is_d ? blockIdx.x : blockIdx.x - half;
    int e = (bb * 4 + wid) * 2 + h;
    const int stride = half * 8;
    const int En = 150000;
    float acc = 0.f;
    if (is_d) {
      int4 ei = (e < En) ? *reinterpret_cast<const int4*>(a.ud + (size_t)e * 4)
                         : make_int4(0, 0, 0, 0);
      for (; e < En; e += stride) {
        int en = e + stride;
        int4 ein = (en < En) ? *reinterpret_cast<const int4*>(a.ud + (size_t)en * 4)
                             : make_int4(0, 0, 0, 0);
        uint2 av = reinterpret_cast<const uint2*>(a.feb + (size_t)ei.x * 128)[l];
        uint2 bv = reinterpret_cast<const uint2*>(a.feb + (size_t)ei.y * 128)[l];
        uint2 rv = reinterpret_cast<const uint2*>(a.relb + (size_t)ei.w * 128)[l];
        float2 a0 = bfpair(av.x), a1 = bfpair(av.y);
        float2 b0 = bfpair(bv.x), b1 = bfpair(bv.y);
        float2 r0 = bfpair(rv.x), r1 = bfpair(rv.y);
        float d = r0.x * ftanh(a0.x + b0.x) + r0.y * ftanh(a0.y + b0.y)
                + r1.x * ftanh(a1.x + b1.x) + r1.y * ftanh(a1.y + b1.y);
#pragma unroll
        for (int o = 1; o < 32; o <<= 1) d += __shfl_xor(d, o);
        if (l == 0) acc += softplus_neg((float)ei.z * d);
        ei = ein;
      }
    } else {
      int3 ei = make_int3(0, 0, 0);
      if (e < En) { ei.x = a.us[(size_t)e * 3]; ei.y = a.us[(size_t)e * 3 + 1]; ei.z = a.us[(size_t)e * 3 + 2]; }
      for (; e < En; e += stride) {
        int en = e + stride;
        int3 ein = make_int3(0, 0, 0);
        if (en < En) { ein.x = a.us[(size_t)en * 3]; ein.y = a.us[(size_t)en * 3 + 1]; ein.z = a.us[(size_t)en * 3 + 2]; }
        uint2 av = reinterpret_cast<const uint2*>(a.feb + (size_t)ei.x * 128)[l];
        uint2 bv = reinterpret_cast<const uint2*>(a.feb + (size_t)ei.y * 128)[l];
        float2 a0 = bfpair(av.x), a1 = bfpair(av.y);
        float2 b0 = bfpair(bv.x), b1 = bfpair(bv.y);
        float d = a0.x * b0.x + a0.y * b0.y + a1.x * b1.x + a1.y * b1.y;
#pragma unroll
        for (int o = 1; o < 32; o <<= 1) d += __shfl_xor(d, o);
        if (l == 0) acc += softplus_neg((float)ei.z * d);
        ei = ein;
      }
    }
    if (l == 0) red8[wid * 2 + h] = acc;
    __syncthreads();
    if (tid == 0) {
      float s = 0.f;
#pragma unroll
      for (int i = 0; i < 8; ++i) s += red8[i];
      a.partial[blockIdx.x] = s;
    }
  }
  grid_barrier(a.cnt, a.gen, a.nblk);
  // phase E: final reduce (block 0)
  if (blockIdx.x == 0) {
    float s = 0.f;
    for (int i = tid; i < a.nblk; i += 256) s += a.partial[i];
    tsm[tid] = s; __syncthreads();
    for (int st = 128; st > 0; st >>= 1) { if (tid < st) tsm[tid] += tsm[tid + st]; __syncthreads(); }
    float total = tsm[0]; __syncthreads();
    const int ns_[5] = {3000, 8000, 6000, 8000, 3000};
#pragma unroll
    for (int seg = 0; seg < 5; ++seg) {
      const float* v = a.cebuf + seg * 8000;
      float q = 0.f;
      for (int i = tid; i < ns_[seg]; i += 256) q += v[i];
      tsm[tid] = q; __syncthreads();
      for (int st = 128; st > 0; st >>= 1) { if (tid < st) tsm[tid] += tsm[tid + st]; __syncthreads(); }
      if (tid == 0) total -= tsm[0] / (float)ns_[seg];
      __syncthreads();
    }
    if (tid == 0) a.outp[0] = total;
  }
}

// ---------------------------------------------------------------------------
extern "C" void kernel_launch(void* const* d_in, const int* in_sizes, int n_in,
                              void* d_out, int out_size, void* d_ws, size_t ws_size,
                              hipStream_t stream)
{
  const float* feat_P = (const float*)d_in[0];
  const float* feat_V = (const float*)d_in[1];
  const float* feat_C = (const float*)d_in[2];
  const float* feat_A = (const float*)d_in[3];
  const float* W1 = (const float*)d_in[4];
  const float* b1 = (const float*)d_in[5];
  const float* W2 = (const float*)d_in[6];
  const float* b2 = (const float*)d_in[7];
  const float* W3 = (const float*)d_in[8];
  const float* b3 = (const float*)d_in[9];
  const float* L00W = (const float*)d_in[10];
  const float* L00b = (const float*)d_in[11];
  const float* L01W = (const float*)d_in[12];
  const float* L01b = (const float*)d_in[13];
  const float* L10W = (const float*)d_in[14];
  const float* L10b = (const float*)d_in[15];
  const float* L11W = (const float*)d_in[16];
  const float* L11b = (const float*)d_in[17];
  const float* L12W = (const float*)d_in[18];
  const float* L12b = (const float*)d_in[19];
  const float* g0_Wih = (const float*)d_in[20];
  const float* g0_Whh = (const float*)d_in[21];
  const float* g0_bih = (const float*)d_in[22];
  const float* g0_bhh = (const float*)d_in[23];
  const float* g1_Wih = (const float*)d_in[24];
  const float* g1_Whh = (const float*)d_in[25];
  const float* g1_bih = (const float*)d_in[26];
  const float* g1_bhh = (const float*)d_in[27];
  const float* rel_emb = (const float*)d_in[28];
  const float* adj00 = (const float*)d_in[29];
  const float* adj01 = (const float*)d_in[30];
  const float* adj10 = (const float*)d_in[31];
  const float* adj11 = (const float*)d_in[32];
  const float* adj12 = (const float*)d_in[33];
  const float* clsA = (const float*)d_in[34];
  const float* clsP = (const float*)d_in[35];
  const float* clsV = (const float*)d_in[36];
  const int* u_s = (const int*)d_in[37];
  const int* u_d = (const int*)d_in[38];

  float* out = (float*)d_out;
  float* fe = out + 1;
  float* rel_out = out + 1 + 18500 * 128;

  float* ws = (float*)d_ws;
  size_t o = 0;
  auto alloc = [&](size_t n) { float* p = ws + o; o += n; return p; };
  float* selfb   = alloc((size_t)18500 * 128);
  float* stcat   = alloc((size_t)18500 * 128);   // P0|V1|C1|A0
  float* stP1    = alloc((size_t)8000 * 128);
  float* scaled0 = alloc((size_t)3000 * 128);
  float* scaled1 = alloc((size_t)8000 * 128);
  float* scaled2 = alloc((size_t)6000 * 128);
  float* scaled3 = alloc((size_t)8000 * 128);
  float* scaled4 = alloc((size_t)3000 * 128);
  float* cebuf   = alloc(5 * 8000);
  float* s0b = alloc(18500);
  float* s1b = alloc(18500);
  float* den = alloc(16);
  float* partial = alloc(1024);
  unsigned* barrier_mem = (unsigned*)alloc(4);   // [0]=cnt, [1]=gen
  auto allocb = [&](size_t nelem) { unsigned short* p = (unsigned short*)(ws + o); o += (nelem + 1) / 2; return p; };
  unsigned short* featb  = allocb((size_t)18500 * 128);
  unsigned short* stcatb = allocb((size_t)18500 * 128);
  unsigned short* stP1b  = allocb((size_t)8000 * 128);
  unsigned short* feb    = allocb((size_t)18500 * 128);
  unsigned short* h0b    = allocb((size_t)8000 * 128);
  unsigned short* h2b    = allocb((size_t)8000 * 128);
  unsigned short* h1b    = allocb((size_t)6000 * 128);
  unsigned short* h3b    = allocb((size_t)3000 * 128);
  unsigned short* h4b    = allocb((size_t)1500 * 128);
  unsigned short* gib    = allocb((size_t)26500 * 384);
  unsigned short* lg0b   = allocb((size_t)3000 * 1500);
  unsigned short* lg2b   = allocb((size_t)6000 * 1500);
  unsigned short* lg1b   = allocb((size_t)8000 * 1500);  // stage 1 (and 4 reuse)
  unsigned short* lg3b   = allocb((size_t)8000 * 1500);  // stage 3
  unsigned short* relb   = allocb(12 * 128);
  unsigned short* W1b = allocb(128 * 128);
  unsigned short* L00Wb = allocb(1500 * 128);
  unsigned short* L01Wb = allocb(1500 * 128);
  unsigned short* L10Wb = allocb(1500 * 128);
  unsigned short* L11Wb = allocb(1500 * 128);
  unsigned short* L12Wb = allocb(1500 * 128);
  unsigned short* g0Wihb = allocb(384 * 128);
  unsigned short* g0Whhb = allocb(384 * 128);
  unsigned short* g1Wihb = allocb(384 * 128);
  unsigned short* g1Whhb = allocb(384 * 128);
  unsigned short* featPb = featb;
  unsigned short* featVb = featb + (size_t)8000 * 128;
  unsigned short* featCb = featb + (size_t)11000 * 128;
  unsigned short* featAb = featb + (size_t)12500 * 128;
  float* stP0 = stcat;
  float* stV1 = stcat + (size_t)8000 * 128;
  float* stC1 = stcat + (size_t)11000 * 128;
  float* stA0 = stcat + (size_t)12500 * 128;
  unsigned short* stP0b = stcatb;
  unsigned short* stV1b = stcatb + (size_t)8000 * 128;
  unsigned short* stC1b = stcatb + (size_t)11000 * 128;
  unsigned short* stA0b = stcatb + (size_t)12500 * 128;
  (void)ws_size; (void)in_sizes; (void)n_in; (void)out_size;

  dim3 blk(256);
  const int NBLK = 1024;
  unsigned* cnt = barrier_mem;
  unsigned* gen = barrier_mem + 1;
  const size_t giOff[5] = {0, 8000, 14000, 22000, 25000};

  // --- 1. batched f32->bf16 conversion (+ zero barrier counter) ---
  CvtArgs ca{};
  int nseg = 0, totblk = 0;
  auto addseg = [&](const float* src, unsigned short* dst, int n) {
    ca.seg[nseg].src = src; ca.seg[nseg].dst = dst; ca.seg[nseg].n = n;
    ca.seg[nseg].nblk = (n + 1023) / 1024; totblk += ca.seg[nseg].nblk; ++nseg;
  };
  addseg(feat_P, featPb, 8000 * 128);
  addseg(feat_V, featVb, 3000 * 128);
  addseg(feat_C, featCb, 1500 * 128);
  addseg(feat_A, featAb, 6000 * 128);
  addseg(W1, W1b, 128 * 128);
  addseg(L00W, L00Wb, 1500 * 128);
  addseg(L01W, L01Wb, 1500 * 128);
  addseg(L10W, L10Wb, 1500 * 128);
  addseg(L11W, L11Wb, 1500 * 128);
  addseg(L12W, L12Wb, 1500 * 128);
  addseg(g0_Wih, g0Wihb, 384 * 128);
  addseg(g0_Whh, g0Whhb, 384 * 128);
  addseg(g1_Wih, g1Wihb, 384 * 128);
  addseg(g1_Whh, g1Whhb, 384 * 128);
  addseg(rel_emb, relb, 12 * 128);
  ca.nseg = nseg;
  hipLaunchKernelGGL(convert_bf16_many, dim3(totblk), blk, 0, stream, ca, cnt);

  // --- 2. static GEMMs: self(f32) + 5x gi(bf16) + stage-0/2 logits(bf16) ---
  {
    GSegs gs{};
    int nb = 0, k = 0;
    auto add = [&](const unsigned short* X, const unsigned short* W, const float* bias,
                   float* C, unsigned short* Cb, int N, int O) {
      int xb = (N + 127) / 128, yb = (O + 63) / 64;
      gs.s[k] = GSeg{X, W, bias, C, Cb, N, O, nb, xb};
      nb += xb * yb; ++k;
    };
    add(featb,  W1b,    b1,     selfb, nullptr,              18500, 128);
    add(featPb, g0Wihb, g0_bih, nullptr, gib + giOff[0] * 384, 8000, 384);
    add(featAb, g0Wihb, g0_bih, nullptr, gib + giOff[1] * 384, 6000, 384);
    add(featPb, g1Wihb, g1_bih, nullptr, gib + giOff[2] * 384, 8000, 384);
    add(featVb, g1Wihb, g1_bih, nullptr, gib + giOff[3] * 384, 3000, 384);
    add(featCb, g1Wihb, g1_bih, nullptr, gib + giOff[4] * 384, 1500, 384);
    add(featVb, L00Wb,  L00b,   nullptr, lg0b,                3000, 1500);
    add(featAb, L10Wb,  L10b,   nullptr, lg2b,                6000, 1500);
    gs.nseg = k;
    hipLaunchKernelGGL(gemm_bf16_gseg, dim3(nb), blk, 0, stream, gs);
  }

  // --- 3. persistent stage 0+2 ---
  {
    StageArgs sa{};
    sa.r0 = RoSeg{(const unsigned*)lg0b, clsV, feat_V, scaled0, cebuf + 0 * 8000, 3000};
    sa.r1 = RoSeg{(const unsigned*)lg2b, clsA, feat_A, scaled2, cebuf + 2 * 8000, 6000};
    sa.s0 = SpSeg{adj00, scaled0, h0b, 8000, 3000};
    sa.s1 = SpSeg{adj10, scaled2, h2b, 8000, 6000};
    sa.g0 = GrSeg{g0Whhb, g0_bhh, gib + giOff[0] * 384, h0b, stP0, stP0b, 8000};
    sa.g1 = GrSeg{g1Whhb, g1_bhh, gib + giOff[2] * 384, h2b, stP1, stP1b, 8000};
    sa.two = 1; sa.cnt = cnt; sa.gen = gen; sa.nblk = NBLK;
    hipLaunchKernelGGL(stage_kernel, dim3(NBLK), blk, 0, stream, sa);
  }
  // --- 4. logits stages 1+3 ---
  {
    GSegs gs{};
    gs.s[0] = GSeg{stP0b, L01Wb, L01b, nullptr, lg1b, 8000, 1500, 0,    63};
    gs.s[1] = GSeg{stP1b, L11Wb, L11b, nullptr, lg3b, 8000, 1500, 1512, 63};
    gs.nseg = 2;
    hipLaunchKernelGGL(gemm_bf16_gseg, dim3(3024), blk, 0, stream, gs);
  }
  // --- 5. persistent stage 1+3 ---
  {
    StageArgs sa{};
    sa.r0 = RoSeg{(const unsigned*)lg1b, clsP, stP0, scaled1, cebuf + 1 * 8000, 8000};
    sa.r1 = RoSeg{(const unsigned*)lg3b, clsP, stP1, scaled3, cebuf + 3 * 8000, 8000};
    sa.s0 = SpSeg{adj01, scaled1, h1b, 6000, 8000};
    sa.s1 = SpSeg{adj11, scaled3, h3b, 3000, 8000};
    sa.g0 = GrSeg{g0Whhb, g0_bhh, gib + giOff[1] * 384, h1b, stA0, stA0b, 6000};
    sa.g1 = GrSeg{g1Whhb, g1_bhh, gib + giOff[3] * 384, h3b, stV1, stV1b, 3000};
    sa.two = 1; sa.cnt = cnt; sa.gen = gen; sa.nblk = NBLK;
    hipLaunchKernelGGL(stage_kernel, dim3(NBLK), blk, 0, stream, sa);
  }
  // --- 6. logits stage 4 ---
  {
    GSegs gs{};
    gs.s[0] = GSeg{stV1b, L12Wb, L12b, nullptr, lg1b, 3000, 1500, 0, 24};
    gs.nseg = 1;
    hipLaunchKernelGGL(gemm_bf16_gseg, dim3(24 * 24), blk, 0, stream, gs);
  }
  // --- 7. persistent stage 4 ---
  {
    StageArgs sa{};
    sa.r0 = RoSeg{(const unsigned*)lg1b, clsV, stV1, scaled4, cebuf + 4 * 8000, 3000};
    sa.s0 = SpSeg{adj12, scaled4, h4b, 1500, 3000};
    sa.g0 = GrSeg{g1Whhb, g1_bhh, gib + giOff[4] * 384, h4b, stC1, stC1b, 1500};
    sa.two = 0; sa.cnt = cnt; sa.gen = gen; sa.nblk = NBLK;
    hipLaunchKernelGGL(stage_kernel, dim3(NBLK), blk, 0, stream, sa);
  }
  // --- 8. persistent tail: scores -> denom -> emb -> edges -> final ---
  {
    TailArgs ta{};
    ta.e0 = selfb; ta.e1 = stcat;
    ta.W2 = W2; ta.b2 = b2; ta.W3 = W3; ta.b3 = b3;
    ta.sc0 = s0b; ta.sc1 = s1b; ta.den = den;
    ta.rel = rel_emb; ta.fe = fe; ta.feb = feb; ta.rel_out = rel_out;
    ta.ud = u_d; ta.us = u_s; ta.relb = relb;
    ta.partial = partial; ta.cebuf = cebuf; ta.outp = out;
    ta.cnt = cnt; ta.gen = gen; ta.nblk = NBLK;
    hipLaunchKernelGGL(tail_kernel, dim3(NBLK), blk, 0, stream, ta);
  }
}

// Round 12
// 495.831 us; speedup vs baseline: 5.9330x; 5.9330x over previous
//
#include <hip/hip_runtime.h>
#include <cstdint>
#include <cstddef>

#define DEV_INLINE __device__ __forceinline__

typedef __attribute__((ext_vector_type(8))) short bf16x8;
typedef __attribute__((ext_vector_type(16))) float f32x16;
struct __align__(8) US4 { unsigned short u[4]; };

DEV_INLINE unsigned short f2bf(float x) {
  unsigned u = __float_as_uint(x);
  return (unsigned short)((u + 0x7FFFu + ((u >> 16) & 1u)) >> 16);
}
DEV_INLINE float bf2f(unsigned short u) { return __uint_as_float(((unsigned)u) << 16); }
DEV_INLINE float2 bfpair(unsigned v) {
  return make_float2(__uint_as_float(v << 16), __uint_as_float(v & 0xFFFF0000u));
}
DEV_INLINE float ftanh(float x) {
  float e = __expf(2.0f * x);
  return 1.0f - 2.0f / (e + 1.0f);
}
DEV_INLINE float softplus_neg(float x) {
  return (x >= 0.f) ? log1pf(__expf(-x)) : (-x + log1pf(__expf(x)));
}

// ---------------------------------------------------------------------------
// Batched f32 -> bf16 conversion
// ---------------------------------------------------------------------------
struct CvtSeg { const float* src; unsigned short* dst; int n; int nblk; };
struct CvtArgs { CvtSeg seg[16]; int nseg; };

__global__ __launch_bounds__(256) void convert_bf16_many(CvtArgs args) {
  int b = blockIdx.x;
  int s = 0;
  while (s < args.nseg && b >= args.seg[s].nblk) { b -= args.seg[s].nblk; ++s; }
  if (s >= args.nseg) return;
  int base = b * 1024 + threadIdx.x * 4;
  if (base >= args.seg[s].n) return;
  float4 v = *reinterpret_cast<const float4*>(args.seg[s].src + base);
  US4 o;
  o.u[0] = f2bf(v.x); o.u[1] = f2bf(v.y); o.u[2] = f2bf(v.z); o.u[3] = f2bf(v.w);
  *reinterpret_cast<US4*>(args.seg[s].dst + base) = o;
}

// ---------------------------------------------------------------------------
// bf16 MFMA GEMM: C = X @ W^T + bias; per-seg f32 (C) or bf16 (Cb) output.
// ---------------------------------------------------------------------------
struct GSeg { const unsigned short* X; const unsigned short* W; const float* bias;
              float* C; unsigned short* Cb; int N; int O; int blk0; int xblk; };
struct GSegs { GSeg s[8]; int nseg; };

__global__ __launch_bounds__(256) void gemm_bf16_gseg(GSegs gs) {
  __shared__ __align__(16) unsigned short Xs[128 * 128];
  __shared__ __align__(16) unsigned short Ws[64 * 128];
  int bx = blockIdx.x;
  int si = 0;
  while (si + 1 < gs.nseg && bx >= gs.s[si + 1].blk0) ++si;
  const GSeg& g = gs.s[si];
  int b = bx - g.blk0;
  int bm = (b % g.xblk) * 128;
  int bn = (b / g.xblk) * 64;
  const int tid = threadIdx.x;

#pragma unroll
  for (int i = 0; i < 8; ++i) {
    int s = tid + 256 * i;
    int row = s >> 4, c16 = s & 15;
    uint4 v = make_uint4(0, 0, 0, 0);
    int gr = bm + row;
    if (gr < g.N) v = *reinterpret_cast<const uint4*>(g.X + (size_t)gr * 128 + c16 * 8);
    *reinterpret_cast<uint4*>(&Xs[(row * 16 + (c16 ^ (row & 7))) * 8]) = v;
  }
#pragma unroll
  for (int i = 0; i < 4; ++i) {
    int s = tid + 256 * i;
    int row = s >> 4, c16 = s & 15;
    uint4 v = make_uint4(0, 0, 0, 0);
    int gw = bn + row;
    if (gw < g.O) v = *reinterpret_cast<const uint4*>(g.W + (size_t)gw * 128 + c16 * 8);
    *reinterpret_cast<uint4*>(&Ws[(row * 16 + (c16 ^ (row & 7))) * 8]) = v;
  }
  __syncthreads();

  const int wave = tid >> 6, lane = tid & 63;
  const int l31 = lane & 31, lhi = lane >> 5;

  f32x16 acc0, acc1;
#pragma unroll
  for (int i = 0; i < 16; ++i) { acc0[i] = 0.f; acc1[i] = 0.f; }
  const int ar = wave * 32 + l31;
#pragma unroll
  for (int ks = 0; ks < 8; ++ks) {
    int c16 = ks * 2 + lhi;
    bf16x8 a  = *reinterpret_cast<const bf16x8*>(&Xs[(ar * 16 + (c16 ^ (ar & 7))) * 8]);
    bf16x8 b0 = *reinterpret_cast<const bf16x8*>(&Ws[(l31 * 16 + (c16 ^ (l31 & 7))) * 8]);
    int br1 = 32 + l31;
    bf16x8 b1 = *reinterpret_cast<const bf16x8*>(&Ws[(br1 * 16 + (c16 ^ (br1 & 7))) * 8]);
    acc0 = __builtin_amdgcn_mfma_f32_32x32x16_bf16(a, b0, acc0, 0, 0, 0);
    acc1 = __builtin_amdgcn_mfma_f32_32x32x16_bf16(a, b1, acc1, 0, 0, 0);
  }

  if (g.Cb) {
#pragma unroll
    for (int reg = 0; reg < 16; ++reg) {
      int r = bm + wave * 32 + (reg & 3) + 8 * (reg >> 2) + 4 * lhi;
      if (r < g.N) {
        int c0 = bn + l31;
        if (c0 < g.O) g.Cb[(size_t)r * g.O + c0] = f2bf(acc0[reg] + g.bias[c0]);
        int c1 = bn + 32 + l31;
        if (c1 < g.O) g.Cb[(size_t)r * g.O + c1] = f2bf(acc1[reg] + g.bias[c1]);
      }
    }
  } else {
#pragma unroll
    for (int reg = 0; reg < 16; ++reg) {
      int r = bm + wave * 32 + (reg & 3) + 8 * (reg >> 2) + 4 * lhi;
      if (r < g.N) {
        int c0 = bn + l31;
        if (c0 < g.O) g.C[(size_t)r * g.O + c0] = acc0[reg] + g.bias[c0];
        int c1 = bn + 32 + l31;
        if (c1 < g.O) g.C[(size_t)r * g.O + c1] = acc1[reg] + g.bias[c1];
      }
    }
  }
}

// ---------------------------------------------------------------------------
// Sparse row scan: block (4 waves) per row; bf16 H output only.
// ---------------------------------------------------------------------------
DEV_INLINE void spmv_body_b(const float* __restrict__ A, const float* __restrict__ Xs,
                            unsigned short* __restrict__ Hb, int row, int K,
                            float (*red)[128])
{
  int tid = threadIdx.x, wave = tid >> 6, lane = tid & 63;
  const float4* Arow = reinterpret_cast<const float4*>(A + (size_t)row * K);
  int K4 = K >> 2;
  float acc0 = 0.f, acc1 = 0.f;
  int base = wave * 64;
  int q = base + lane;
  float4 a = (base < K4 && q < K4) ? Arow[q] : make_float4(0.f, 0.f, 0.f, 0.f);
  for (; base < K4; base += 256) {
    int nb = base + 256;
    int nq = nb + lane;
    float4 an = (nb < K4 && nq < K4) ? Arow[nq] : make_float4(0.f, 0.f, 0.f, 0.f);
#pragma unroll
    for (int c = 0; c < 4; ++c) {
      float av = (c == 0) ? a.x : (c == 1) ? a.y : (c == 2) ? a.z : a.w;
      unsigned long long mm = __ballot(av != 0.f);
      while (mm) {
        int b = __builtin_ctzll(mm);
        mm &= mm - 1;
        float v = __shfl(av, b);
        int jj = (base + b) * 4 + c;
        const float* xr = Xs + (size_t)jj * 128;
        acc0 += v * xr[lane];
        acc1 += v * xr[lane + 64];
      }
    }
    a = an;
  }
  red[wave][lane] = acc0;
  red[wave][lane + 64] = acc1;
  __syncthreads();
  if (wave == 0) {
    float r0 = red[0][lane] + red[1][lane] + red[2][lane] + red[3][lane];
    float r1 = red[0][lane + 64] + red[1][lane + 64] + red[2][lane + 64] + red[3][lane + 64];
    Hb[(size_t)row * 128 + lane] = f2bf(r0);
    Hb[(size_t)row * 128 + 64 + lane] = f2bf(r1);
  }
}

__global__ __launch_bounds__(256) void spmv_scan(
    const float* __restrict__ A, const float* __restrict__ Xs,
    unsigned short* __restrict__ Hb, int M, int K)
{
  __shared__ float red[4][128];
  spmv_body_b(A, Xs, Hb, blockIdx.x, K, red);
}

__global__ __launch_bounds__(256) void spmv_scan2(
    const float* __restrict__ A0, const float* __restrict__ X0,
    unsigned short* __restrict__ H0b, int M0, int K0,
    const float* __restrict__ A1, const float* __restrict__ X1,
    unsigned short* __restrict__ H1b, int K1)
{
  __shared__ float red[4][128];
  if ((int)blockIdx.x < M0) spmv_body_b(A0, X0, H0b, blockIdx.x, K0, red);
  else                      spmv_body_b(A1, X1, H1b, blockIdx.x - M0, K1, red);
}

// ---------------------------------------------------------------------------
// Fused gh-GEMM + GRU (32-row tile; bf16 H and gi; h re-read from LDS tile)
// ---------------------------------------------------------------------------
DEV_INLINE void ghgru_body_b(
    const unsigned short* __restrict__ Hb, const unsigned short* __restrict__ Whhb,
    const float* __restrict__ bhh, const unsigned short* __restrict__ gi,
    float* __restrict__ out, unsigned short* __restrict__ outb,
    int M, int bm, unsigned short* As)
{
  const int tid = threadIdx.x;
#pragma unroll
  for (int i = 0; i < 2; ++i) {
    int s = tid + 256 * i;
    int row = s >> 4, c16 = s & 15;
    uint4 v = make_uint4(0, 0, 0, 0);
    int gr = bm + row;
    if (gr < M) v = *reinterpret_cast<const uint4*>(Hb + (size_t)gr * 128 + c16 * 8);
    *reinterpret_cast<uint4*>(&As[(row * 16 + (c16 ^ (row & 7))) * 8]) = v;
  }
  __syncthreads();

  const int wave = tid >> 6, lane = tid & 63;
  const int l31 = lane & 31, lhi = lane >> 5;
  const int d = wave * 32 + l31;

  f32x16 ar, az, an;
#pragma unroll
  for (int i = 0; i < 16; ++i) { ar[i] = 0.f; az[i] = 0.f; an[i] = 0.f; }

#pragma unroll
  for (int ks = 0; ks < 8; ++ks) {
    int c16 = ks * 2 + lhi;
    bf16x8 a = *reinterpret_cast<const bf16x8*>(&As[(l31 * 16 + (c16 ^ (l31 & 7))) * 8]);
    const unsigned short* wb = Whhb + (size_t)c16 * 8;
    bf16x8 br = *reinterpret_cast<const bf16x8*>(wb + (size_t)d * 128);
    bf16x8 bz = *reinterpret_cast<const bf16x8*>(wb + (size_t)(128 + d) * 128);
    bf16x8 bn = *reinterpret_cast<const bf16x8*>(wb + (size_t)(256 + d) * 128);
    ar = __builtin_amdgcn_mfma_f32_32x32x16_bf16(a, br, ar, 0, 0, 0);
    az = __builtin_amdgcn_mfma_f32_32x32x16_bf16(a, bz, az, 0, 0, 0);
    an = __builtin_amdgcn_mfma_f32_32x32x16_bf16(a, bn, an, 0, 0, 0);
  }

  const float b_r = bhh[d], b_z = bhh[128 + d], b_n = bhh[256 + d];
#pragma unroll
  for (int reg = 0; reg < 16; ++reg) {
    int rowl = (reg & 3) + 8 * (reg >> 2) + 4 * lhi;
    int r = bm + rowl;
    if (r < M) {
      const unsigned short* gir = gi + (size_t)r * 384;
      float rr = 1.f / (1.f + __expf(-(bf2f(gir[d]) + ar[reg] + b_r)));
      float zz = 1.f / (1.f + __expf(-(bf2f(gir[128 + d]) + az[reg] + b_z)));
      float nn = ftanh(bf2f(gir[256 + d]) + rr * (an[reg] + b_n));
      float h = bf2f(As[(rowl * 16 + ((d >> 3) ^ (rowl & 7))) * 8 + (d & 7)]);
      float o = (1.f - zz) * nn + zz * h;
      out[(size_t)r * 128 + d] = o;
      outb[(size_t)r * 128 + d] = f2bf(o);
    }
  }
}

__global__ __launch_bounds__(256) void gh_gru(
    const unsigned short* __restrict__ Hb, const unsigned short* __restrict__ Whhb,
    const float* __restrict__ bhh, const unsigned short* __restrict__ gi,
    float* __restrict__ out, unsigned short* __restrict__ outb, int M)
{
  __shared__ __align__(16) unsigned short As[32 * 128];
  ghgru_body_b(Hb, Whhb, bhh, gi, out, outb, M, blockIdx.x * 32, As);
}

__global__ __launch_bounds__(256) void gh_gru2(
    const unsigned short* Hb0, const unsigned short* Whh0, const float* bhh0,
    const unsigned short* gi0, float* out0, unsigned short* outb0, int M0, int nblk0,
    const unsigned short* Hb1, const unsigned short* Whh1, const float* bhh1,
    const unsigned short* gi1, float* out1, unsigned short* outb1, int M1)
{
  __shared__ __align__(16) unsigned short As[32 * 128];
  if ((int)blockIdx.x < nblk0)
    ghgru_body_b(Hb0, Whh0, bhh0, gi0, out0, outb0, M0, blockIdx.x * 32, As);
  else
    ghgru_body_b(Hb1, Whh1, bhh1, gi1, out1, outb1, M1, (blockIdx.x - nblk0) * 32, As);
}

// ---------------------------------------------------------------------------
// Wave-per-row softmax / CE / tcp from bf16 logits (750 bf16-pairs / row)
// ---------------------------------------------------------------------------
DEV_INLINE void rowops_body_b(int lane, const unsigned* __restrict__ lrb,
                              const float2* __restrict__ cr2,
                              const float* __restrict__ srcrow,
                              float* __restrict__ scaledrow, float* __restrict__ cep)
{
  float2 e[12];
  float m = -3.4e38f;
#pragma unroll
  for (int k = 0; k < 12; ++k) {
    int idx = k * 64 + lane;
    if (idx < 750) {
      e[k] = bfpair(lrb[idx]);
      m = fmaxf(m, fmaxf(e[k].x, e[k].y));
    } else {
      e[k] = make_float2(-3.4e38f, -3.4e38f);
    }
  }
#pragma unroll
  for (int o = 1; o < 64; o <<= 1) m = fmaxf(m, __shfl_xor(m, o));
  float z = 0.f;
#pragma unroll
  for (int k = 0; k < 12; ++k) {
    e[k].x = __expf(e[k].x - m); e[k].y = __expf(e[k].y - m);
    z += e[k].x + e[k].y;
  }
#pragma unroll
  for (int o = 1; o < 64; o <<= 1) z += __shfl_xor(z, o);
  float invZ1 = 1.0f / z;
  float m2 = invZ1;
  float t = 0.f, ls = 0.f, z2 = 0.f;
#pragma unroll
  for (int k = 0; k < 12; ++k) {
    int idx = k * 64 + lane;
    if (idx < 750) {
      float2 c = cr2[idx];
      float px = e[k].x * invZ1, py = e[k].y * invZ1;
      t  += c.x * px + c.y * py;
      ls += c.x + c.y;
      z2 += __expf(px - m2) + __expf(py - m2);
    }
  }
#pragma unroll
  for (int o = 1; o < 64; o <<= 1) {
    t += __shfl_xor(t, o); ls += __shfl_xor(ls, o); z2 += __shfl_xor(z2, o);
  }
  if (lane == 0) *cep = t - ls * (m2 + logf(z2));
  scaledrow[lane]      = t * srcrow[lane];
  scaledrow[lane + 64] = t * srcrow[lane + 64];
}

__global__ __launch_bounds__(256) void rowops2b(
    const unsigned* lgA, const float* clsA_, const float* srcA, float* scA, float* ceA, int nA,
    const unsigned* lgB, const float* clsB_, const float* srcB, float* scB, float* ceB, int nB)
{
  int gw = (blockIdx.x * 256 + threadIdx.x) >> 6;
  if (gw >= nA + nB) return;
  int lane = threadIdx.x & 63;
  if (gw < nA) {
    rowops_body_b(lane, lgA + (size_t)gw * 750,
                  reinterpret_cast<const float2*>(clsA_ + (size_t)gw * 1500),
                  srcA + (size_t)gw * 128, scA + (size_t)gw * 128, ceA + gw);
  } else {
    int r = gw - nA;
    rowops_body_b(lane, lgB + (size_t)r * 750,
                  reinterpret_cast<const float2*>(clsB_ + (size_t)r * 1500),
                  srcB + (size_t)r * 128, scB + (size_t)r * 128, ceB + r);
  }
}

__global__ __launch_bounds__(256) void rowops1b(
    const unsigned* lg, const float* cls, const float* src, float* sc, float* ce, int n)
{
  int gw = (blockIdx.x * 256 + threadIdx.x) >> 6;
  if (gw >= n) return;
  int lane = threadIdx.x & 63;
  rowops_body_b(lane, lg + (size_t)gw * 750,
                reinterpret_cast<const float2*>(cls + (size_t)gw * 1500),
                src + (size_t)gw * 128, sc + (size_t)gw * 128, ce + gw);
}

// ---------------------------------------------------------------------------
// Fuse pipeline
// ---------------------------------------------------------------------------
__global__ __launch_bounds__(256) void fuse_scores_all(
    const float* __restrict__ e0, const float* __restrict__ e1,
    const float* __restrict__ W2, const float* __restrict__ b2,
    const float* __restrict__ W3, const float* __restrict__ b3,
    float* __restrict__ s0, float* __restrict__ s1)
{
  int lane = threadIdx.x & 63;
  int row = (blockIdx.x * 256 + threadIdx.x) >> 6;
  if (row >= 18500) return;
  float a0 = e0[(size_t)row * 128 + lane] * W2[lane] + e0[(size_t)row * 128 + 64 + lane] * W2[64 + lane];
  float a1 = e1[(size_t)row * 128 + lane] * W3[lane] + e1[(size_t)row * 128 + 64 + lane] * W3[64 + lane];
#pragma unroll
  for (int o = 32; o > 0; o >>= 1) { a0 += __shfl_down(a0, o); a1 += __shfl_down(a1, o); }
  if (lane == 0) {
    s0[row] = fmaxf(a0 + b2[0], 0.f);
    s1[row] = fmaxf(a1 + b3[0], 0.f);
  }
}

__global__ __launch_bounds__(1024) void denom4(
    const float* __restrict__ s0, const float* __restrict__ s1,
    float* __restrict__ den)
{
  __shared__ float red[1024];
  const int ns[4]   = {8000, 3000, 1500, 6000};
  const int offs[4] = {0, 8000, 11000, 12500};
  int b = blockIdx.x;
  int n = ns[b];
  const float* p0 = s0 + offs[b];
  const float* p1 = s1 + offs[b];
  int tid = threadIdx.x;
  float m = -3.4e38f;
  for (int i = tid; i < n; i += 1024) m = fmaxf(m, p0[i]);
  red[tid] = m; __syncthreads();
  for (int s = 512; s > 0; s >>= 1) { if (tid < s) red[tid] = fmaxf(red[tid], red[tid + s]); __syncthreads(); }
  float m0 = red[0]; __syncthreads();
  float z = 0.f;
  for (int i = tid; i < n; i += 1024) z += __expf(p0[i] - m0);
  red[tid] = z; __syncthreads();
  for (int s = 512; s > 0; s >>= 1) { if (tid < s) red[tid] += red[tid + s]; __syncthreads(); }
  float Z0 = red[0]; __syncthreads();
  m = -3.4e38f;
  for (int i = tid; i < n; i += 1024) m = fmaxf(m, p1[i]);
  red[tid] = m; __syncthreads();
  for (int s = 512; s > 0; s >>= 1) { if (tid < s) red[tid] = fmaxf(red[tid], red[tid + s]); __syncthreads(); }
  float m1 = red[0]; __syncthreads();
  z = 0.f;
  for (int i = tid; i < n; i += 1024) z += __expf(p1[i] - m1);
  red[tid] = z; __syncthreads();
  for (int s = 512; s > 0; s >>= 1) { if (tid < s) red[tid] += red[tid + s]; __syncthreads(); }
  if (tid == 0) { den[b * 4] = m0; den[b * 4 + 1] = Z0; den[b * 4 + 2] = m1; den[b * 4 + 3] = red[0]; }
}

__global__ __launch_bounds__(256) void fuse_emb_all(
    const float* __restrict__ e0, const float* __restrict__ e1,
    const float* __restrict__ s0, const float* __restrict__ s1,
    const float* __restrict__ den, const float* __restrict__ rel,
    float* __restrict__ fe, unsigned short* __restrict__ feb,
    float* __restrict__ rel_out)
{
  int t = blockIdx.x * 256 + threadIdx.x;
  const int tot2 = 18500 * 64;
  if (t < tot2) {
    int idx = t * 2;
    int row = idx >> 7;
    int e = (row < 8000) ? 0 : (row < 11000) ? 1 : (row < 12500) ? 2 : 3;
    float a0 = __expf(s0[row] - den[e * 4]) / den[e * 4 + 1];
    float a1 = __expf(s1[row] - den[e * 4 + 2]) / den[e * 4 + 3];
    float2 v0 = *reinterpret_cast<const float2*>(e0 + idx);
    float2 v1 = *reinterpret_cast<const float2*>(e1 + idx);
    float r0 = fmaxf(a0 * v0.x + a1 * v1.x, 0.f);
    float r1 = fmaxf(a0 * v0.y + a1 * v1.y, 0.f);
    *reinterpret_cast<float2*>(fe + idx) = make_float2(r0, r1);
    unsigned pb = (unsigned)f2bf(r0) | ((unsigned)f2bf(r1) << 16);
    *reinterpret_cast<unsigned*>(feb + idx) = pb;
  } else if (t < tot2 + 768) {
    int k = (t - tot2) * 2;
    *reinterpret_cast<float2*>(rel_out + k) = *reinterpret_cast<const float2*>(rel + k);
  }
}

// ---------------------------------------------------------------------------
// Edge losses: half-wave per edge, fast tanh, index prefetch.
// ---------------------------------------------------------------------------
__global__ __launch_bounds__(256) void edge_both(
    const int* __restrict__ ud, const int* __restrict__ us,
    const unsigned short* __restrict__ feb, const unsigned short* __restrict__ relb,
    float* __restrict__ partial, int En)
{
  const int tid = threadIdx.x;
  const int lane = tid & 63;
  const int l = lane & 31, h = lane >> 5;
  const int wid = tid >> 6;
  bool is_d = (blockIdx.x < 1024);
  int bb = is_d ? blockIdx.x : blockIdx.x - 1024;
  int e = (bb * 4 + wid) * 2 + h;
  const int ns = 1024 * 4 * 2;
  float acc = 0.f;
  if (is_d) {
    int4 ei = (e < En) ? *reinterpret_cast<const int4*>(ud + (size_t)e * 4)
                       : make_int4(0, 0, 0, 0);
    for (; e < En; e += ns) {
      int en = e + ns;
      int4 ein = (en < En) ? *reinterpret_cast<const int4*>(ud + (size_t)en * 4)
                           : make_int4(0, 0, 0, 0);
      uint2 a = reinterpret_cast<const uint2*>(feb + (size_t)ei.x * 128)[l];
      uint2 b = reinterpret_cast<const uint2*>(feb + (size_t)ei.y * 128)[l];
      uint2 r = reinterpret_cast<const uint2*>(relb + (size_t)ei.w * 128)[l];
      float2 a0 = bfpair(a.x), a1 = bfpair(a.y);
      float2 b0 = bfpair(b.x), b1 = bfpair(b.y);
      float2 r0 = bfpair(r.x), r1 = bfpair(r.y);
      float d = r0.x * ftanh(a0.x + b0.x) + r0.y * ftanh(a0.y + b0.y)
              + r1.x * ftanh(a1.x + b1.x) + r1.y * ftanh(a1.y + b1.y);
#pragma unroll
      for (int o = 1; o < 32; o <<= 1) d += __shfl_xor(d, o);
      if (l == 0) acc += softplus_neg((float)ei.z * d);
      ei = ein;
    }
  } else {
    int3 ei = make_int3(0, 0, 0);
    if (e < En) { ei.x = us[(size_t)e * 3]; ei.y = us[(size_t)e * 3 + 1]; ei.z = us[(size_t)e * 3 + 2]; }
    for (; e < En; e += ns) {
      int en = e + ns;
      int3 ein = make_int3(0, 0, 0);
      if (en < En) { ein.x = us[(size_t)en * 3]; ein.y = us[(size_t)en * 3 + 1]; ein.z = us[(size_t)en * 3 + 2]; }
      uint2 a = reinterpret_cast<const uint2*>(feb + (size_t)ei.x * 128)[l];
      uint2 b = reinterpret_cast<const uint2*>(feb + (size_t)ei.y * 128)[l];
      float2 a0 = bfpair(a.x), a1 = bfpair(a.y);
      float2 b0 = bfpair(b.x), b1 = bfpair(b.y);
      float d = a0.x * b0.x + a0.y * b0.y + a1.x * b1.x + a1.y * b1.y;
#pragma unroll
      for (int o = 1; o < 32; o <<= 1) d += __shfl_xor(d, o);
      if (l == 0) acc += softplus_neg((float)ei.z * d);
      ei = ein;
    }
  }
  __shared__ float red[8];
  if (l == 0) red[wid * 2 + h] = acc;
  __syncthreads();
  if (tid == 0) {
    float s = 0.f;
#pragma unroll
    for (int i = 0; i < 8; ++i) s += red[i];
    partial[blockIdx.x] = s;
  }
}

__global__ __launch_bounds__(1024) void final_reduce(
    const float* __restrict__ partial, const float* __restrict__ cebuf,
    float* __restrict__ out)
{
  __shared__ float red[1024];
  __shared__ float total;
  int tid = threadIdx.x;
  if (tid == 0) total = 0.f;
  __syncthreads();
  float a = partial[tid] + partial[tid + 1024];
  red[tid] = a; __syncthreads();
  for (int s = 512; s > 0; s >>= 1) { if (tid < s) red[tid] += red[tid + s]; __syncthreads(); }
  if (tid == 0) total += red[0];
  __syncthreads();
  const int ns[5] = {3000, 8000, 6000, 8000, 3000};
#pragma unroll
  for (int seg = 0; seg < 5; ++seg) {
    const float* v = cebuf + seg * 8000;
    float s = 0.f;
    for (int i = tid; i < ns[seg]; i += 1024) s += v[i];
    red[tid] = s; __syncthreads();
    for (int st = 512; st > 0; st >>= 1) { if (tid < st) red[tid] += red[tid + st]; __syncthreads(); }
    if (tid == 0) total -= red[0] / (float)ns[seg];
    __syncthreads();
  }
  if (tid == 0) out[0] = total;
}

// ---------------------------------------------------------------------------
extern "C" void kernel_launch(void* const* d_in, const int* in_sizes, int n_in,
                              void* d_out, int out_size, void* d_ws, size_t ws_size,
                              hipStream_t stream)
{
  const float* feat_P = (const float*)d_in[0];
  const float* feat_V = (const float*)d_in[1];
  const float* feat_C = (const float*)d_in[2];
  const float* feat_A = (const float*)d_in[3];
  const float* W1 = (const float*)d_in[4];
  const float* b1 = (const float*)d_in[5];
  const float* W2 = (const float*)d_in[6];
  const float* b2 = (const float*)d_in[7];
  const float* W3 = (const float*)d_in[8];
  const float* b3 = (const float*)d_in[9];
  const float* L00W = (const float*)d_in[10];
  const float* L00b = (const float*)d_in[11];
  const float* L01W = (const float*)d_in[12];
  const float* L01b = (const float*)d_in[13];
  const float* L10W = (const float*)d_in[14];
  const float* L10b = (const float*)d_in[15];
  const float* L11W = (const float*)d_in[16];
  const float* L11b = (const float*)d_in[17];
  const float* L12W = (const float*)d_in[18];
  const float* L12b = (const float*)d_in[19];
  const float* g0_Wih = (const float*)d_in[20];
  const float* g0_Whh = (const float*)d_in[21];
  const float* g0_bih = (const float*)d_in[22];
  const float* g0_bhh = (const float*)d_in[23];
  const float* g1_Wih = (const float*)d_in[24];
  const float* g1_Whh = (const float*)d_in[25];
  const float* g1_bih = (const float*)d_in[26];
  const float* g1_bhh = (const float*)d_in[27];
  const float* rel_emb = (const float*)d_in[28];
  const float* adj00 = (const float*)d_in[29];
  const float* adj01 = (const float*)d_in[30];
  const float* adj10 = (const float*)d_in[31];
  const float* adj11 = (const float*)d_in[32];
  const float* adj12 = (const float*)d_in[33];
  const float* clsA = (const float*)d_in[34];
  const float* clsP = (const float*)d_in[35];
  const float* clsV = (const float*)d_in[36];
  const int* u_s = (const int*)d_in[37];
  const int* u_d = (const int*)d_in[38];

  float* out = (float*)d_out;
  float* fe = out + 1;
  float* rel_out = out + 1 + 18500 * 128;

  float* ws = (float*)d_ws;
  size_t o = 0;
  auto alloc = [&](size_t n) { float* p = ws + o; o += n; return p; };
  float* selfb   = alloc((size_t)18500 * 128);
  float* stcat   = alloc((size_t)18500 * 128);   // P0|V1|C1|A0
  float* stP1    = alloc((size_t)8000 * 128);
  float* scaled0 = alloc((size_t)3000 * 128);
  float* scaled1 = alloc((size_t)8000 * 128);
  float* scaled2 = alloc((size_t)6000 * 128);
  float* scaled3 = alloc((size_t)8000 * 128);
  float* scaled4 = alloc((size_t)3000 * 128);
  float* cebuf   = alloc(5 * 8000);
  float* s0b = alloc(18500);
  float* s1b = alloc(18500);
  float* den = alloc(16);
  float* partial = alloc(2048);
  auto allocb = [&](size_t nelem) { unsigned short* p = (unsigned short*)(ws + o); o += (nelem + 1) / 2; return p; };
  unsigned short* featb  = allocb((size_t)18500 * 128);
  unsigned short* stcatb = allocb((size_t)18500 * 128);
  unsigned short* stP1b  = allocb((size_t)8000 * 128);
  unsigned short* feb    = allocb((size_t)18500 * 128);
  unsigned short* h0b    = allocb((size_t)8000 * 128);
  unsigned short* h2b    = allocb((size_t)8000 * 128);
  unsigned short* h1b    = allocb((size_t)6000 * 128);
  unsigned short* h3b    = allocb((size_t)3000 * 128);
  unsigned short* h4b    = allocb((size_t)1500 * 128);
  unsigned short* gib    = allocb((size_t)26500 * 384);
  unsigned short* lg0b   = allocb((size_t)3000 * 1500);
  unsigned short* lg2b   = allocb((size_t)6000 * 1500);
  unsigned short* lg1b   = allocb((size_t)8000 * 1500);  // stage 1 (and 4 reuse)
  unsigned short* lg3b   = allocb((size_t)8000 * 1500);  // stage 3
  unsigned short* relb   = allocb(12 * 128);
  unsigned short* W1b = allocb(128 * 128);
  unsigned short* L00Wb = allocb(1500 * 128);
  unsigned short* L01Wb = allocb(1500 * 128);
  unsigned short* L10Wb = allocb(1500 * 128);
  unsigned short* L11Wb = allocb(1500 * 128);
  unsigned short* L12Wb = allocb(1500 * 128);
  unsigned short* g0Wihb = allocb(384 * 128);
  unsigned short* g0Whhb = allocb(384 * 128);
  unsigned short* g1Wihb = allocb(384 * 128);
  unsigned short* g1Whhb = allocb(384 * 128);
  unsigned short* featPb = featb;
  unsigned short* featVb = featb + (size_t)8000 * 128;
  unsigned short* featCb = featb + (size_t)11000 * 128;
  unsigned short* featAb = featb + (size_t)12500 * 128;
  float* stP0 = stcat;
  float* stV1 = stcat + (size_t)8000 * 128;
  float* stC1 = stcat + (size_t)11000 * 128;
  float* stA0 = stcat + (size_t)12500 * 128;
  unsigned short* stP0b = stcatb;
  unsigned short* stV1b = stcatb + (size_t)8000 * 128;
  unsigned short* stC1b = stcatb + (size_t)11000 * 128;
  unsigned short* stA0b = stcatb + (size_t)12500 * 128;
  (void)ws_size; (void)in_sizes; (void)n_in; (void)out_size;

  dim3 blk(256);
  const size_t giOff[5] = {0, 8000, 14000, 22000, 25000};

  // --- 1. batched f32->bf16 conversion ---
  CvtArgs ca{};
  int nseg = 0, totblk = 0;
  auto addseg = [&](const float* src, unsigned short* dst, int n) {
    ca.seg[nseg].src = src; ca.seg[nseg].dst = dst; ca.seg[nseg].n = n;
    ca.seg[nseg].nblk = (n + 1023) / 1024; totblk += ca.seg[nseg].nblk; ++nseg;
  };
  addseg(feat_P, featPb, 8000 * 128);
  addseg(feat_V, featVb, 3000 * 128);
  addseg(feat_C, featCb, 1500 * 128);
  addseg(feat_A, featAb, 6000 * 128);
  addseg(W1, W1b, 128 * 128);
  addseg(L00W, L00Wb, 1500 * 128);
  addseg(L01W, L01Wb, 1500 * 128);
  addseg(L10W, L10Wb, 1500 * 128);
  addseg(L11W, L11Wb, 1500 * 128);
  addseg(L12W, L12Wb, 1500 * 128);
  addseg(g0_Wih, g0Wihb, 384 * 128);
  addseg(g0_Whh, g0Whhb, 384 * 128);
  addseg(g1_Wih, g1Wihb, 384 * 128);
  addseg(g1_Whh, g1Whhb, 384 * 128);
  addseg(rel_emb, relb, 12 * 128);
  ca.nseg = nseg;
  hipLaunchKernelGGL(convert_bf16_many, dim3(totblk), blk, 0, stream, ca);

  // --- 2. static GEMMs: self(f32) + 5x gi(bf16) + stage-0/2 logits(bf16) ---
  {
    GSegs gs{};
    int nb = 0, k = 0;
    auto add = [&](const unsigned short* X, const unsigned short* W, const float* bias,
                   float* C, unsigned short* Cb, int N, int O) {
      int xb = (N + 127) / 128, yb = (O + 63) / 64;
      gs.s[k] = GSeg{X, W, bias, C, Cb, N, O, nb, xb};
      nb += xb * yb; ++k;
    };
    add(featb,  W1b,    b1,     selfb, nullptr,                18500, 128);
    add(featPb, g0Wihb, g0_bih, nullptr, gib + giOff[0] * 384, 8000, 384);
    add(featAb, g0Wihb, g0_bih, nullptr, gib + giOff[1] * 384, 6000, 384);
    add(featPb, g1Wihb, g1_bih, nullptr, gib + giOff[2] * 384, 8000, 384);
    add(featVb, g1Wihb, g1_bih, nullptr, gib + giOff[3] * 384, 3000, 384);
    add(featCb, g1Wihb, g1_bih, nullptr, gib + giOff[4] * 384, 1500, 384);
    add(featVb, L00Wb,  L00b,   nullptr, lg0b,                 3000, 1500);
    add(featAb, L10Wb,  L10b,   nullptr, lg2b,                 6000, 1500);
    gs.nseg = k;
    hipLaunchKernelGGL(gemm_bf16_gseg, dim3(nb), blk, 0, stream, gs);
  }

  // --- 3. rowops stages 0+2 (bf16 logits) ---
  hipLaunchKernelGGL(rowops2b, dim3((9000 * 64 + 255) / 256), blk, 0, stream,
                     (const unsigned*)lg0b, clsV, feat_V, scaled0, cebuf + 0 * 8000, 3000,
                     (const unsigned*)lg2b, clsA, feat_A, scaled2, cebuf + 2 * 8000, 6000);
  // --- 4. spmv stages 0+2 ---
  hipLaunchKernelGGL(spmv_scan2, dim3(16000), blk, 0, stream,
                     adj00, scaled0, h0b, 8000, 3000,
                     adj10, scaled2, h2b, 6000);
  // --- 5. gh_gru stages 0+2 -> stP0, stP1 ---
  hipLaunchKernelGGL(gh_gru2, dim3(500), blk, 0, stream,
                     h0b, g0Whhb, g0_bhh, gib + giOff[0] * 384, stP0, stP0b, 8000, 250,
                     h2b, g1Whhb, g1_bhh, gib + giOff[2] * 384, stP1, stP1b, 8000);
  // --- 6. logits stages 1+3 (bf16 out) ---
  {
    GSegs gs{};
    gs.s[0] = GSeg{stP0b, L01Wb, L01b, nullptr, lg1b, 8000, 1500, 0,    63};
    gs.s[1] = GSeg{stP1b, L11Wb, L11b, nullptr, lg3b, 8000, 1500, 1512, 63};
    gs.nseg = 2;
    hipLaunchKernelGGL(gemm_bf16_gseg, dim3(3024), blk, 0, stream, gs);
  }
  // --- 7. rowops stages 1+3 ---
  hipLaunchKernelGGL(rowops2b, dim3((16000 * 64 + 255) / 256), blk, 0, stream,
                     (const unsigned*)lg1b, clsP, stP0, scaled1, cebuf + 1 * 8000, 8000,
                     (const unsigned*)lg3b, clsP, stP1, scaled3, cebuf + 3 * 8000, 8000);
  // --- 8. spmv stages 1+3 ---
  hipLaunchKernelGGL(spmv_scan2, dim3(9000), blk, 0, stream,
                     adj01, scaled1, h1b, 6000, 8000,
                     adj11, scaled3, h3b, 8000);
  // --- 9. gh_gru stages 1+3 -> stA0, stV1 ---
  hipLaunchKernelGGL(gh_gru2, dim3(188 + 94), blk, 0, stream,
                     h1b, g0Whhb, g0_bhh, gib + giOff[1] * 384, stA0, stA0b, 6000, 188,
                     h3b, g1Whhb, g1_bhh, gib + giOff[3] * 384, stV1, stV1b, 3000);
  // --- 10-13. stage 4 ---
  {
    GSegs gs{};
    gs.s[0] = GSeg{stV1b, L12Wb, L12b, nullptr, lg1b, 3000, 1500, 0, 24};
    gs.nseg = 1;
    hipLaunchKernelGGL(gemm_bf16_gseg, dim3(24 * 24), blk, 0, stream, gs);
  }
  hipLaunchKernelGGL(rowops1b, dim3((3000 * 64 + 255) / 256), blk, 0, stream,
                     (const unsigned*)lg1b, clsV, stV1, scaled4, cebuf + 4 * 8000, 3000);
  hipLaunchKernelGGL(spmv_scan, dim3(1500), blk, 0, stream, adj12, scaled4, h4b, 1500, 3000);
  hipLaunchKernelGGL(gh_gru, dim3(47), blk, 0, stream,
                     h4b, g1Whhb, g1_bhh, gib + giOff[4] * 384, stC1, stC1b, 1500);

  // --- 14-16. fuse pipeline ---
  hipLaunchKernelGGL(fuse_scores_all, dim3((18500 + 3) / 4), blk, 0, stream,
                     selfb, stcat, W2, b2, W3, b3, s0b, s1b);
  hipLaunchKernelGGL(denom4, dim3(4), dim3(1024), 0, stream, s0b, s1b, den);
  hipLaunchKernelGGL(fuse_emb_all, dim3((18500 * 64 + 768 + 255) / 256), blk, 0, stream,
                     selfb, stcat, s0b, s1b, den, rel_emb, fe, feb, rel_out);

  // --- 17. edges ---
  hipLaunchKernelGGL(edge_both, dim3(2048), blk, 0, stream, u_d, u_s, feb, relb, partial, 150000);

  // --- 18. final ---
  hipLaunchKernelGGL(final_reduce, dim3(1), dim3(1024), 0, stream, partial, cebuf, out);
}

// Round 13
// 490.238 us; speedup vs baseline: 6.0007x; 1.0114x over previous
//
#include <hip/hip_runtime.h>
#include <cstdint>
#include <cstddef>

#define DEV_INLINE __device__ __forceinline__

typedef __attribute__((ext_vector_type(8))) short bf16x8;
typedef __attribute__((ext_vector_type(16))) float f32x16;
struct __align__(8) US4 { unsigned short u[4]; };

DEV_INLINE unsigned short f2bf(float x) {
  unsigned u = __float_as_uint(x);
  return (unsigned short)((u + 0x7FFFu + ((u >> 16) & 1u)) >> 16);
}
DEV_INLINE float bf2f(unsigned short u) { return __uint_as_float(((unsigned)u) << 16); }
DEV_INLINE float2 bfpair(unsigned v) {
  return make_float2(__uint_as_float(v << 16), __uint_as_float(v & 0xFFFF0000u));
}
DEV_INLINE float ftanh(float x) {
  float e = __expf(2.0f * x);
  return 1.0f - 2.0f / (e + 1.0f);
}
DEV_INLINE float softplus_neg(float x) {
  return (x >= 0.f) ? log1pf(__expf(-x)) : (-x + log1pf(__expf(x)));
}

// ---------------------------------------------------------------------------
// Batched f32 -> bf16 conversion
// ---------------------------------------------------------------------------
struct CvtSeg { const float* src; unsigned short* dst; int n; int nblk; };
struct CvtArgs { CvtSeg seg[16]; int nseg; };

__global__ __launch_bounds__(256) void convert_bf16_many(CvtArgs args) {
  int b = blockIdx.x;
  int s = 0;
  while (s < args.nseg && b >= args.seg[s].nblk) { b -= args.seg[s].nblk; ++s; }
  if (s >= args.nseg) return;
  int base = b * 1024 + threadIdx.x * 4;
  if (base >= args.seg[s].n) return;
  float4 v = *reinterpret_cast<const float4*>(args.seg[s].src + base);
  US4 o;
  o.u[0] = f2bf(v.x); o.u[1] = f2bf(v.y); o.u[2] = f2bf(v.z); o.u[3] = f2bf(v.w);
  *reinterpret_cast<US4*>(args.seg[s].dst + base) = o;
}

// ---------------------------------------------------------------------------
// bf16 MFMA GEMM: C = X @ W^T + bias; per-seg f32 (C) or bf16 (Cb) output.
// ---------------------------------------------------------------------------
struct GSeg { const unsigned short* X; const unsigned short* W; const float* bias;
              float* C; unsigned short* Cb; int N; int O; int blk0; int xblk; };
struct GSegs { GSeg s[8]; int nseg; };

__global__ __launch_bounds__(256) void gemm_bf16_gseg(GSegs gs) {
  __shared__ __align__(16) unsigned short Xs[128 * 128];
  __shared__ __align__(16) unsigned short Ws[64 * 128];
  int bx = blockIdx.x;
  int si = 0;
  while (si + 1 < gs.nseg && bx >= gs.s[si + 1].blk0) ++si;
  const GSeg& g = gs.s[si];
  int b = bx - g.blk0;
  int bm = (b % g.xblk) * 128;
  int bn = (b / g.xblk) * 64;
  const int tid = threadIdx.x;

#pragma unroll
  for (int i = 0; i < 8; ++i) {
    int s = tid + 256 * i;
    int row = s >> 4, c16 = s & 15;
    uint4 v = make_uint4(0, 0, 0, 0);
    int gr = bm + row;
    if (gr < g.N) v = *reinterpret_cast<const uint4*>(g.X + (size_t)gr * 128 + c16 * 8);
    *reinterpret_cast<uint4*>(&Xs[(row * 16 + (c16 ^ (row & 7))) * 8]) = v;
  }
#pragma unroll
  for (int i = 0; i < 4; ++i) {
    int s = tid + 256 * i;
    int row = s >> 4, c16 = s & 15;
    uint4 v = make_uint4(0, 0, 0, 0);
    int gw = bn + row;
    if (gw < g.O) v = *reinterpret_cast<const uint4*>(g.W + (size_t)gw * 128 + c16 * 8);
    *reinterpret_cast<uint4*>(&Ws[(row * 16 + (c16 ^ (row & 7))) * 8]) = v;
  }
  __syncthreads();

  const int wave = tid >> 6, lane = tid & 63;
  const int l31 = lane & 31, lhi = lane >> 5;

  f32x16 acc0, acc1;
#pragma unroll
  for (int i = 0; i < 16; ++i) { acc0[i] = 0.f; acc1[i] = 0.f; }
  const int ar = wave * 32 + l31;
#pragma unroll
  for (int ks = 0; ks < 8; ++ks) {
    int c16 = ks * 2 + lhi;
    bf16x8 a  = *reinterpret_cast<const bf16x8*>(&Xs[(ar * 16 + (c16 ^ (ar & 7))) * 8]);
    bf16x8 b0 = *reinterpret_cast<const bf16x8*>(&Ws[(l31 * 16 + (c16 ^ (l31 & 7))) * 8]);
    int br1 = 32 + l31;
    bf16x8 b1 = *reinterpret_cast<const bf16x8*>(&Ws[(br1 * 16 + (c16 ^ (br1 & 7))) * 8]);
    acc0 = __builtin_amdgcn_mfma_f32_32x32x16_bf16(a, b0, acc0, 0, 0, 0);
    acc1 = __builtin_amdgcn_mfma_f32_32x32x16_bf16(a, b1, acc1, 0, 0, 0);
  }

  if (g.Cb) {
#pragma unroll
    for (int reg = 0; reg < 16; ++reg) {
      int r = bm + wave * 32 + (reg & 3) + 8 * (reg >> 2) + 4 * lhi;
      if (r < g.N) {
        int c0 = bn + l31;
        if (c0 < g.O) g.Cb[(size_t)r * g.O + c0] = f2bf(acc0[reg] + g.bias[c0]);
        int c1 = bn + 32 + l31;
        if (c1 < g.O) g.Cb[(size_t)r * g.O + c1] = f2bf(acc1[reg] + g.bias[c1]);
      }
    }
  } else {
#pragma unroll
    for (int reg = 0; reg < 16; ++reg) {
      int r = bm + wave * 32 + (reg & 3) + 8 * (reg >> 2) + 4 * lhi;
      if (r < g.N) {
        int c0 = bn + l31;
        if (c0 < g.O) g.C[(size_t)r * g.O + c0] = acc0[reg] + g.bias[c0];
        int c1 = bn + 32 + l31;
        if (c1 < g.O) g.C[(size_t)r * g.O + c1] = acc1[reg] + g.bias[c1];
      }
    }
  }
}

// ---------------------------------------------------------------------------
// Sparse row scan: block (4 waves) per row; bf16 H output only.
// ---------------------------------------------------------------------------
DEV_INLINE void spmv_body_b(const float* __restrict__ A, const float* __restrict__ Xs,
                            unsigned short* __restrict__ Hb, int row, int K,
                            float (*red)[128])
{
  int tid = threadIdx.x, wave = tid >> 6, lane = tid & 63;
  const float4* Arow = reinterpret_cast<const float4*>(A + (size_t)row * K);
  int K4 = K >> 2;
  float acc0 = 0.f, acc1 = 0.f;
  int base = wave * 64;
  int q = base + lane;
  float4 a = (base < K4 && q < K4) ? Arow[q] : make_float4(0.f, 0.f, 0.f, 0.f);
  for (; base < K4; base += 256) {
    int nb = base + 256;
    int nq = nb + lane;
    float4 an = (nb < K4 && nq < K4) ? Arow[nq] : make_float4(0.f, 0.f, 0.f, 0.f);
#pragma unroll
    for (int c = 0; c < 4; ++c) {
      float av = (c == 0) ? a.x : (c == 1) ? a.y : (c == 2) ? a.z : a.w;
      unsigned long long mm = __ballot(av != 0.f);
      while (mm) {
        int b = __builtin_ctzll(mm);
        mm &= mm - 1;
        float v = __shfl(av, b);
        int jj = (base + b) * 4 + c;
        const float* xr = Xs + (size_t)jj * 128;
        acc0 += v * xr[lane];
        acc1 += v * xr[lane + 64];
      }
    }
    a = an;
  }
  red[wave][lane] = acc0;
  red[wave][lane + 64] = acc1;
  __syncthreads();
  if (wave == 0) {
    float r0 = red[0][lane] + red[1][lane] + red[2][lane] + red[3][lane];
    float r1 = red[0][lane + 64] + red[1][lane + 64] + red[2][lane + 64] + red[3][lane + 64];
    Hb[(size_t)row * 128 + lane] = f2bf(r0);
    Hb[(size_t)row * 128 + 64 + lane] = f2bf(r1);
  }
}

__global__ __launch_bounds__(256) void spmv_scan(
    const float* __restrict__ A, const float* __restrict__ Xs,
    unsigned short* __restrict__ Hb, int M, int K)
{
  __shared__ float red[4][128];
  spmv_body_b(A, Xs, Hb, blockIdx.x, K, red);
}

__global__ __launch_bounds__(256) void spmv_scan2(
    const float* __restrict__ A0, const float* __restrict__ X0,
    unsigned short* __restrict__ H0b, int M0, int K0,
    const float* __restrict__ A1, const float* __restrict__ X1,
    unsigned short* __restrict__ H1b, int K1)
{
  __shared__ float red[4][128];
  if ((int)blockIdx.x < M0) spmv_body_b(A0, X0, H0b, blockIdx.x, K0, red);
  else                      spmv_body_b(A1, X1, H1b, blockIdx.x - M0, K1, red);
}

// ---------------------------------------------------------------------------
// Fused gh-GEMM + GRU (32-row tile; bf16 H/gi; bf16 state out only)
// ---------------------------------------------------------------------------
DEV_INLINE void ghgru_body_b(
    const unsigned short* __restrict__ Hb, const unsigned short* __restrict__ Whhb,
    const float* __restrict__ bhh, const unsigned short* __restrict__ gi,
    unsigned short* __restrict__ outb, int M, int bm, unsigned short* As)
{
  const int tid = threadIdx.x;
#pragma unroll
  for (int i = 0; i < 2; ++i) {
    int s = tid + 256 * i;
    int row = s >> 4, c16 = s & 15;
    uint4 v = make_uint4(0, 0, 0, 0);
    int gr = bm + row;
    if (gr < M) v = *reinterpret_cast<const uint4*>(Hb + (size_t)gr * 128 + c16 * 8);
    *reinterpret_cast<uint4*>(&As[(row * 16 + (c16 ^ (row & 7))) * 8]) = v;
  }
  __syncthreads();

  const int wave = tid >> 6, lane = tid & 63;
  const int l31 = lane & 31, lhi = lane >> 5;
  const int d = wave * 32 + l31;

  f32x16 ar, az, an;
#pragma unroll
  for (int i = 0; i < 16; ++i) { ar[i] = 0.f; az[i] = 0.f; an[i] = 0.f; }

#pragma unroll
  for (int ks = 0; ks < 8; ++ks) {
    int c16 = ks * 2 + lhi;
    bf16x8 a = *reinterpret_cast<const bf16x8*>(&As[(l31 * 16 + (c16 ^ (l31 & 7))) * 8]);
    const unsigned short* wb = Whhb + (size_t)c16 * 8;
    bf16x8 br = *reinterpret_cast<const bf16x8*>(wb + (size_t)d * 128);
    bf16x8 bz = *reinterpret_cast<const bf16x8*>(wb + (size_t)(128 + d) * 128);
    bf16x8 bn = *reinterpret_cast<const bf16x8*>(wb + (size_t)(256 + d) * 128);
    ar = __builtin_amdgcn_mfma_f32_32x32x16_bf16(a, br, ar, 0, 0, 0);
    az = __builtin_amdgcn_mfma_f32_32x32x16_bf16(a, bz, az, 0, 0, 0);
    an = __builtin_amdgcn_mfma_f32_32x32x16_bf16(a, bn, an, 0, 0, 0);
  }

  const float b_r = bhh[d], b_z = bhh[128 + d], b_n = bhh[256 + d];
#pragma unroll
  for (int reg = 0; reg < 16; ++reg) {
    int rowl = (reg & 3) + 8 * (reg >> 2) + 4 * lhi;
    int r = bm + rowl;
    if (r < M) {
      const unsigned short* gir = gi + (size_t)r * 384;
      float rr = 1.f / (1.f + __expf(-(bf2f(gir[d]) + ar[reg] + b_r)));
      float zz = 1.f / (1.f + __expf(-(bf2f(gir[128 + d]) + az[reg] + b_z)));
      float nn = ftanh(bf2f(gir[256 + d]) + rr * (an[reg] + b_n));
      float h = bf2f(As[(rowl * 16 + ((d >> 3) ^ (rowl & 7))) * 8 + (d & 7)]);
      float o = (1.f - zz) * nn + zz * h;
      outb[(size_t)r * 128 + d] = f2bf(o);
    }
  }
}

__global__ __launch_bounds__(256) void gh_gru(
    const unsigned short* __restrict__ Hb, const unsigned short* __restrict__ Whhb,
    const float* __restrict__ bhh, const unsigned short* __restrict__ gi,
    unsigned short* __restrict__ outb, int M)
{
  __shared__ __align__(16) unsigned short As[32 * 128];
  ghgru_body_b(Hb, Whhb, bhh, gi, outb, M, blockIdx.x * 32, As);
}

__global__ __launch_bounds__(256) void gh_gru2(
    const unsigned short* Hb0, const unsigned short* Whh0, const float* bhh0,
    const unsigned short* gi0, unsigned short* outb0, int M0, int nblk0,
    const unsigned short* Hb1, const unsigned short* Whh1, const float* bhh1,
    const unsigned short* gi1, unsigned short* outb1, int M1)
{
  __shared__ __align__(16) unsigned short As[32 * 128];
  if ((int)blockIdx.x < nblk0)
    ghgru_body_b(Hb0, Whh0, bhh0, gi0, outb0, M0, blockIdx.x * 32, As);
  else
    ghgru_body_b(Hb1, Whh1, bhh1, gi1, outb1, M1, (blockIdx.x - nblk0) * 32, As);
}

// ---------------------------------------------------------------------------
// Wave-per-row softmax / CE / tcp; bf16 logits + bf16 src.
// ---------------------------------------------------------------------------
DEV_INLINE void rowops_body_b(int lane, const unsigned* __restrict__ lrb,
                              const float2* __restrict__ cr2,
                              const unsigned* __restrict__ srcb,
                              float* __restrict__ scaledrow, float* __restrict__ cep)
{
  float2 e[12];
  float m = -3.4e38f;
#pragma unroll
  for (int k = 0; k < 12; ++k) {
    int idx = k * 64 + lane;
    if (idx < 750) {
      e[k] = bfpair(lrb[idx]);
      m = fmaxf(m, fmaxf(e[k].x, e[k].y));
    } else {
      e[k] = make_float2(-3.4e38f, -3.4e38f);
    }
  }
#pragma unroll
  for (int o = 1; o < 64; o <<= 1) m = fmaxf(m, __shfl_xor(m, o));
  float z = 0.f;
#pragma unroll
  for (int k = 0; k < 12; ++k) {
    e[k].x = __expf(e[k].x - m); e[k].y = __expf(e[k].y - m);
    z += e[k].x + e[k].y;
  }
#pragma unroll
  for (int o = 1; o < 64; o <<= 1) z += __shfl_xor(z, o);
  float invZ1 = 1.0f / z;
  float m2 = invZ1;
  float t = 0.f, ls = 0.f, z2 = 0.f;
#pragma unroll
  for (int k = 0; k < 12; ++k) {
    int idx = k * 64 + lane;
    if (idx < 750) {
      float2 c = cr2[idx];
      float px = e[k].x * invZ1, py = e[k].y * invZ1;
      t  += c.x * px + c.y * py;
      ls += c.x + c.y;
      z2 += __expf(px - m2) + __expf(py - m2);
    }
  }
#pragma unroll
  for (int o = 1; o < 64; o <<= 1) {
    t += __shfl_xor(t, o); ls += __shfl_xor(ls, o); z2 += __shfl_xor(z2, o);
  }
  if (lane == 0) *cep = t - ls * (m2 + logf(z2));
  float2 sv = bfpair(srcb[lane]);
  *reinterpret_cast<float2*>(scaledrow + lane * 2) = make_float2(t * sv.x, t * sv.y);
}

__global__ __launch_bounds__(256) void rowops2b(
    const unsigned* lgA, const float* clsA_, const unsigned* srcA, float* scA, float* ceA, int nA,
    const unsigned* lgB, const float* clsB_, const unsigned* srcB, float* scB, float* ceB, int nB)
{
  int gw = (blockIdx.x * 256 + threadIdx.x) >> 6;
  if (gw >= nA + nB) return;
  int lane = threadIdx.x & 63;
  if (gw < nA) {
    rowops_body_b(lane, lgA + (size_t)gw * 750,
                  reinterpret_cast<const float2*>(clsA_ + (size_t)gw * 1500),
                  srcA + (size_t)gw * 64, scA + (size_t)gw * 128, ceA + gw);
  } else {
    int r = gw - nA;
    rowops_body_b(lane, lgB + (size_t)r * 750,
                  reinterpret_cast<const float2*>(clsB_ + (size_t)r * 1500),
                  srcB + (size_t)r * 64, scB + (size_t)r * 128, ceB + r);
  }
}

__global__ __launch_bounds__(256) void rowops1b(
    const unsigned* lg, const float* cls, const unsigned* src, float* sc, float* ce, int n)
{
  int gw = (blockIdx.x * 256 + threadIdx.x) >> 6;
  if (gw >= n) return;
  int lane = threadIdx.x & 63;
  rowops_body_b(lane, lg + (size_t)gw * 750,
                reinterpret_cast<const float2*>(cls + (size_t)gw * 1500),
                src + (size_t)gw * 64, sc + (size_t)gw * 128, ce + gw);
}

// stages 1+3 share clsP: one wave handles row r of BOTH stages; cls read once.
__global__ __launch_bounds__(256) void rowops_pairb(
    const unsigned* lg1, const unsigned* lg3, const float* clsP,
    const unsigned* src1, const unsigned* src3,
    float* sc1, float* sc3, float* ce1, float* ce3, int n)
{
  int gw = (blockIdx.x * 256 + threadIdx.x) >> 6;
  if (gw >= n) return;
  int lane = threadIdx.x & 63;
  const unsigned* l1 = lg1 + (size_t)gw * 750;
  const unsigned* l3 = lg3 + (size_t)gw * 750;
  const float2* cr2 = reinterpret_cast<const float2*>(clsP + (size_t)gw * 1500);

  float2 e1[12], e3[12];
  float m1 = -3.4e38f, m3 = -3.4e38f;
#pragma unroll
  for (int k = 0; k < 12; ++k) {
    int idx = k * 64 + lane;
    if (idx < 750) {
      e1[k] = bfpair(l1[idx]);
      e3[k] = bfpair(l3[idx]);
      m1 = fmaxf(m1, fmaxf(e1[k].x, e1[k].y));
      m3 = fmaxf(m3, fmaxf(e3[k].x, e3[k].y));
    } else {
      e1[k] = make_float2(-3.4e38f, -3.4e38f);
      e3[k] = make_float2(-3.4e38f, -3.4e38f);
    }
  }
#pragma unroll
  for (int o = 1; o < 64; o <<= 1) {
    m1 = fmaxf(m1, __shfl_xor(m1, o));
    m3 = fmaxf(m3, __shfl_xor(m3, o));
  }
  float z1 = 0.f, z3 = 0.f;
#pragma unroll
  for (int k = 0; k < 12; ++k) {
    e1[k].x = __expf(e1[k].x - m1); e1[k].y = __expf(e1[k].y - m1);
    e3[k].x = __expf(e3[k].x - m3); e3[k].y = __expf(e3[k].y - m3);
    z1 += e1[k].x + e1[k].y;
    z3 += e3[k].x + e3[k].y;
  }
#pragma unroll
  for (int o = 1; o < 64; o <<= 1) { z1 += __shfl_xor(z1, o); z3 += __shfl_xor(z3, o); }
  float iZ1 = 1.0f / z1, iZ3 = 1.0f / z3;
  float q1 = iZ1, q3 = iZ3;   // m2 for softmax-of-softmax
  float t1 = 0.f, t3 = 0.f, ls = 0.f, w1 = 0.f, w3 = 0.f;
#pragma unroll
  for (int k = 0; k < 12; ++k) {
    int idx = k * 64 + lane;
    if (idx < 750) {
      float2 c = cr2[idx];
      float p1x = e1[k].x * iZ1, p1y = e1[k].y * iZ1;
      float p3x = e3[k].x * iZ3, p3y = e3[k].y * iZ3;
      t1 += c.x * p1x + c.y * p1y;
      t3 += c.x * p3x + c.y * p3y;
      ls += c.x + c.y;
      w1 += __expf(p1x - q1) + __expf(p1y - q1);
      w3 += __expf(p3x - q3) + __expf(p3y - q3);
    }
  }
#pragma unroll
  for (int o = 1; o < 64; o <<= 1) {
    t1 += __shfl_xor(t1, o); t3 += __shfl_xor(t3, o); ls += __shfl_xor(ls, o);
    w1 += __shfl_xor(w1, o); w3 += __shfl_xor(w3, o);
  }
  if (lane == 0) {
    ce1[gw] = t1 - ls * (q1 + logf(w1));
    ce3[gw] = t3 - ls * (q3 + logf(w3));
  }
  float2 s1 = bfpair(src1[(size_t)gw * 64 + lane]);
  float2 s3 = bfpair(src3[(size_t)gw * 64 + lane]);
  *reinterpret_cast<float2*>(sc1 + (size_t)gw * 128 + lane * 2) = make_float2(t1 * s1.x, t1 * s1.y);
  *reinterpret_cast<float2*>(sc3 + (size_t)gw * 128 + lane * 2) = make_float2(t3 * s3.x, t3 * s3.y);
}

// ---------------------------------------------------------------------------
// Fuse pipeline (bf16 e0/e1)
// ---------------------------------------------------------------------------
__global__ __launch_bounds__(256) void fuse_scores_all(
    const unsigned* __restrict__ e0, const unsigned* __restrict__ e1,
    const float* __restrict__ W2, const float* __restrict__ b2,
    const float* __restrict__ W3, const float* __restrict__ b3,
    float* __restrict__ s0, float* __restrict__ s1)
{
  int lane = threadIdx.x & 63;
  int row = (blockIdx.x * 256 + threadIdx.x) >> 6;
  if (row >= 18500) return;
  float2 w2 = *reinterpret_cast<const float2*>(W2 + lane * 2);
  float2 w3 = *reinterpret_cast<const float2*>(W3 + lane * 2);
  float2 v0 = bfpair(e0[(size_t)row * 64 + lane]);
  float2 v1 = bfpair(e1[(size_t)row * 64 + lane]);
  float a0 = v0.x * w2.x + v0.y * w2.y;
  float a1 = v1.x * w3.x + v1.y * w3.y;
#pragma unroll
  for (int o = 32; o > 0; o >>= 1) { a0 += __shfl_down(a0, o); a1 += __shfl_down(a1, o); }
  if (lane == 0) {
    s0[row] = fmaxf(a0 + b2[0], 0.f);
    s1[row] = fmaxf(a1 + b3[0], 0.f);
  }
}

__global__ __launch_bounds__(1024) void denom4(
    const float* __restrict__ s0, const float* __restrict__ s1,
    float* __restrict__ den)
{
  __shared__ float red[1024];
  const int ns[4]   = {8000, 3000, 1500, 6000};
  const int offs[4] = {0, 8000, 11000, 12500};
  int b = blockIdx.x;
  int n = ns[b];
  const float* p0 = s0 + offs[b];
  const float* p1 = s1 + offs[b];
  int tid = threadIdx.x;
  float m = -3.4e38f;
  for (int i = tid; i < n; i += 1024) m = fmaxf(m, p0[i]);
  red[tid] = m; __syncthreads();
  for (int s = 512; s > 0; s >>= 1) { if (tid < s) red[tid] = fmaxf(red[tid], red[tid + s]); __syncthreads(); }
  float m0 = red[0]; __syncthreads();
  float z = 0.f;
  for (int i = tid; i < n; i += 1024) z += __expf(p0[i] - m0);
  red[tid] = z; __syncthreads();
  for (int s = 512; s > 0; s >>= 1) { if (tid < s) red[tid] += red[tid + s]; __syncthreads(); }
  float Z0 = red[0]; __syncthreads();
  m = -3.4e38f;
  for (int i = tid; i < n; i += 1024) m = fmaxf(m, p1[i]);
  red[tid] = m; __syncthreads();
  for (int s = 512; s > 0; s >>= 1) { if (tid < s) red[tid] = fmaxf(red[tid], red[tid + s]); __syncthreads(); }
  float m1 = red[0]; __syncthreads();
  z = 0.f;
  for (int i = tid; i < n; i += 1024) z += __expf(p1[i] - m1);
  red[tid] = z; __syncthreads();
  for (int s = 512; s > 0; s >>= 1) { if (tid < s) red[tid] += red[tid + s]; __syncthreads(); }
  if (tid == 0) { den[b * 4] = m0; den[b * 4 + 1] = Z0; den[b * 4 + 2] = m1; den[b * 4 + 3] = red[0]; }
}

__global__ __launch_bounds__(256) void fuse_emb_all(
    const unsigned* __restrict__ e0, const unsigned* __restrict__ e1,
    const float* __restrict__ s0, const float* __restrict__ s1,
    const float* __restrict__ den, const float* __restrict__ rel,
    float* __restrict__ fe, unsigned short* __restrict__ feb,
    float* __restrict__ rel_out)
{
  int t = blockIdx.x * 256 + threadIdx.x;
  const int tot2 = 18500 * 64;
  if (t < tot2) {
    int idx = t * 2;
    int row = idx >> 7;
    int e = (row < 8000) ? 0 : (row < 11000) ? 1 : (row < 12500) ? 2 : 3;
    float a0 = __expf(s0[row] - den[e * 4]) / den[e * 4 + 1];
    float a1 = __expf(s1[row] - den[e * 4 + 2]) / den[e * 4 + 3];
    float2 v0 = bfpair(e0[t]);
    float2 v1 = bfpair(e1[t]);
    float r0 = fmaxf(a0 * v0.x + a1 * v1.x, 0.f);
    float r1 = fmaxf(a0 * v0.y + a1 * v1.y, 0.f);
    *reinterpret_cast<float2*>(fe + idx) = make_float2(r0, r1);
    unsigned pb = (unsigned)f2bf(r0) | ((unsigned)f2bf(r1) << 16);
    *reinterpret_cast<unsigned*>(feb + idx) = pb;
  } else if (t < tot2 + 768) {
    int k = (t - tot2) * 2;
    *reinterpret_cast<float2*>(rel_out + k) = *reinterpret_cast<const float2*>(rel + k);
  }
}

// ---------------------------------------------------------------------------
// Edge losses: half-wave per edge, fast tanh, 2-deep gather pipeline.
// ---------------------------------------------------------------------------
__global__ __launch_bounds__(256) void edge_both(
    const int* __restrict__ ud, const int* __restrict__ us,
    const unsigned short* __restrict__ feb, const unsigned short* __restrict__ relb,
    float* __restrict__ partial, int En)
{
  const int tid = threadIdx.x;
  const int lane = tid & 63;
  const int l = lane & 31, h = lane >> 5;
  const int wid = tid >> 6;
  bool is_d = (blockIdx.x < 1024);
  int bb = is_d ? blockIdx.x : blockIdx.x - 1024;
  int e = (bb * 4 + wid) * 2 + h;
  const int ns = 1024 * 4 * 2;
  float acc = 0.f;
  if (is_d) {
    int4 ei = (e < En) ? *reinterpret_cast<const int4*>(ud + (size_t)e * 4)
                       : make_int4(0, 0, 0, 0);
    uint2 av = reinterpret_cast<const uint2*>(feb + (size_t)ei.x * 128)[l];
    uint2 bv = reinterpret_cast<const uint2*>(feb + (size_t)ei.y * 128)[l];
    uint2 rv = reinterpret_cast<const uint2*>(relb + (size_t)ei.w * 128)[l];
    for (; e < En; e += ns) {
      int en = e + ns;
      int4 ein = (en < En) ? *reinterpret_cast<const int4*>(ud + (size_t)en * 4)
                           : make_int4(0, 0, 0, 0);
      uint2 avn = reinterpret_cast<const uint2*>(feb + (size_t)ein.x * 128)[l];
      uint2 bvn = reinterpret_cast<const uint2*>(feb + (size_t)ein.y * 128)[l];
      uint2 rvn = reinterpret_cast<const uint2*>(relb + (size_t)ein.w * 128)[l];
      float2 a0 = bfpair(av.x), a1 = bfpair(av.y);
      float2 b0 = bfpair(bv.x), b1 = bfpair(bv.y);
      float2 r0 = bfpair(rv.x), r1 = bfpair(rv.y);
      float d = r0.x * ftanh(a0.x + b0.x) + r0.y * ftanh(a0.y + b0.y)
              + r1.x * ftanh(a1.x + b1.x) + r1.y * ftanh(a1.y + b1.y);
#pragma unroll
      for (int o = 1; o < 32; o <<= 1) d += __shfl_xor(d, o);
      if (l == 0) acc += softplus_neg((float)ei.z * d);
      ei = ein; av = avn; bv = bvn; rv = rvn;
    }
  } else {
    int3 ei = make_int3(0, 0, 0);
    if (e < En) { ei.x = us[(size_t)e * 3]; ei.y = us[(size_t)e * 3 + 1]; ei.z = us[(size_t)e * 3 + 2]; }
    uint2 av = reinterpret_cast<const uint2*>(feb + (size_t)ei.x * 128)[l];
    uint2 bv = reinterpret_cast<const uint2*>(feb + (size_t)ei.y * 128)[l];
    for (; e < En; e += ns) {
      int en = e + ns;
      int3 ein = make_int3(0, 0, 0);
      if (en < En) { ein.x = us[(size_t)en * 3]; ein.y = us[(size_t)en * 3 + 1]; ein.z = us[(size_t)en * 3 + 2]; }
      uint2 avn = reinterpret_cast<const uint2*>(feb + (size_t)ein.x * 128)[l];
      uint2 bvn = reinterpret_cast<const uint2*>(feb + (size_t)ein.y * 128)[l];
      float2 a0 = bfpair(av.x), a1 = bfpair(av.y);
      float2 b0 = bfpair(bv.x), b1 = bfpair(bv.y);
      float d = a0.x * b0.x + a0.y * b0.y + a1.x * b1.x + a1.y * b1.y;
#pragma unroll
      for (int o = 1; o < 32; o <<= 1) d += __shfl_xor(d, o);
      if (l == 0) acc += softplus_neg((float)ei.z * d);
      ei = ein; av = avn; bv = bvn;
    }
  }
  __shared__ float red[8];
  if (l == 0) red[wid * 2 + h] = acc;
  __syncthreads();
  if (tid == 0) {
    float s = 0.f;
#pragma unroll
    for (int i = 0; i < 8; ++i) s += red[i];
    partial[blockIdx.x] = s;
  }
}

__global__ __launch_bounds__(1024) void final_reduce(
    const float* __restrict__ partial, const float* __restrict__ cebuf,
    float* __restrict__ out)
{
  __shared__ float red[1024];
  __shared__ float total;
  int tid = threadIdx.x;
  if (tid == 0) total = 0.f;
  __syncthreads();
  float a = partial[tid] + partial[tid + 1024];
  red[tid] = a; __syncthreads();
  for (int s = 512; s > 0; s >>= 1) { if (tid < s) red[tid] += red[tid + s]; __syncthreads(); }
  if (tid == 0) total += red[0];
  __syncthreads();
  const int ns[5] = {3000, 8000, 6000, 8000, 3000};
#pragma unroll
  for (int seg = 0; seg < 5; ++seg) {
    const float* v = cebuf + seg * 8000;
    float s = 0.f;
    for (int i = tid; i < ns[seg]; i += 1024) s += v[i];
    red[tid] = s; __syncthreads();
    for (int st = 512; st > 0; st >>= 1) { if (tid < st) red[tid] += red[tid + st]; __syncthreads(); }
    if (tid == 0) total -= red[0] / (float)ns[seg];
    __syncthreads();
  }
  if (tid == 0) out[0] = total;
}

// ---------------------------------------------------------------------------
extern "C" void kernel_launch(void* const* d_in, const int* in_sizes, int n_in,
                              void* d_out, int out_size, void* d_ws, size_t ws_size,
                              hipStream_t stream)
{
  const float* feat_P = (const float*)d_in[0];
  const float* feat_V = (const float*)d_in[1];
  const float* feat_C = (const float*)d_in[2];
  const float* feat_A = (const float*)d_in[3];
  const float* W1 = (const float*)d_in[4];
  const float* b1 = (const float*)d_in[5];
  const float* W2 = (const float*)d_in[6];
  const float* b2 = (const float*)d_in[7];
  const float* W3 = (const float*)d_in[8];
  const float* b3 = (const float*)d_in[9];
  const float* L00W = (const float*)d_in[10];
  const float* L00b = (const float*)d_in[11];
  const float* L01W = (const float*)d_in[12];
  const float* L01b = (const float*)d_in[13];
  const float* L10W = (const float*)d_in[14];
  const float* L10b = (const float*)d_in[15];
  const float* L11W = (const float*)d_in[16];
  const float* L11b = (const float*)d_in[17];
  const float* L12W = (const float*)d_in[18];
  const float* L12b = (const float*)d_in[19];
  const float* g0_Wih = (const float*)d_in[20];
  const float* g0_Whh = (const float*)d_in[21];
  const float* g0_bih = (const float*)d_in[22];
  const float* g0_bhh = (const float*)d_in[23];
  const float* g1_Wih = (const float*)d_in[24];
  const float* g1_Whh = (const float*)d_in[25];
  const float* g1_bih = (const float*)d_in[26];
  const float* g1_bhh = (const float*)d_in[27];
  const float* rel_emb = (const float*)d_in[28];
  const float* adj00 = (const float*)d_in[29];
  const float* adj01 = (const float*)d_in[30];
  const float* adj10 = (const float*)d_in[31];
  const float* adj11 = (const float*)d_in[32];
  const float* adj12 = (const float*)d_in[33];
  const float* clsA = (const float*)d_in[34];
  const float* clsP = (const float*)d_in[35];
  const float* clsV = (const float*)d_in[36];
  const int* u_s = (const int*)d_in[37];
  const int* u_d = (const int*)d_in[38];

  float* out = (float*)d_out;
  float* fe = out + 1;
  float* rel_out = out + 1 + 18500 * 128;

  float* ws = (float*)d_ws;
  size_t o = 0;
  auto alloc = [&](size_t n) { float* p = ws + o; o += n; return p; };
  float* scaled0 = alloc((size_t)3000 * 128);
  float* scaled1 = alloc((size_t)8000 * 128);
  float* scaled2 = alloc((size_t)6000 * 128);
  float* scaled3 = alloc((size_t)8000 * 128);
  float* scaled4 = alloc((size_t)3000 * 128);
  float* cebuf   = alloc(5 * 8000);
  float* s0b = alloc(18500);
  float* s1b = alloc(18500);
  float* den = alloc(16);
  float* partial = alloc(2048);
  auto allocb = [&](size_t nelem) { unsigned short* p = (unsigned short*)(ws + o); o += (nelem + 1) / 2; return p; };
  unsigned short* featb  = allocb((size_t)18500 * 128);
  unsigned short* selfbB = allocb((size_t)18500 * 128);
  unsigned short* stcatb = allocb((size_t)18500 * 128);   // P0|V1|C1|A0
  unsigned short* stP1b  = allocb((size_t)8000 * 128);
  unsigned short* feb    = allocb((size_t)18500 * 128);
  unsigned short* h0b    = allocb((size_t)8000 * 128);
  unsigned short* h2b    = allocb((size_t)8000 * 128);
  unsigned short* h1b    = allocb((size_t)6000 * 128);
  unsigned short* h3b    = allocb((size_t)3000 * 128);
  unsigned short* h4b    = allocb((size_t)1500 * 128);
  unsigned short* gib    = allocb((size_t)26500 * 384);
  unsigned short* lg0b   = allocb((size_t)3000 * 1500);
  unsigned short* lg2b   = allocb((size_t)6000 * 1500);
  unsigned short* lg1b   = allocb((size_t)8000 * 1500);  // stage 1 (and 4 reuse)
  unsigned short* lg3b   = allocb((size_t)8000 * 1500);  // stage 3
  unsigned short* relb   = allocb(12 * 128);
  unsigned short* W1b = allocb(128 * 128);
  unsigned short* L00Wb = allocb(1500 * 128);
  unsigned short* L01Wb = allocb(1500 * 128);
  unsigned short* L10Wb = allocb(1500 * 128);
  unsigned short* L11Wb = allocb(1500 * 128);
  unsigned short* L12Wb = allocb(1500 * 128);
  unsigned short* g0Wihb = allocb(384 * 128);
  unsigned short* g0Whhb = allocb(384 * 128);
  unsigned short* g1Wihb = allocb(384 * 128);
  unsigned short* g1Whhb = allocb(384 * 128);
  unsigned short* featPb = featb;
  unsigned short* featVb = featb + (size_t)8000 * 128;
  unsigned short* featCb = featb + (size_t)11000 * 128;
  unsigned short* featAb = featb + (size_t)12500 * 128;
  unsigned short* stP0b = stcatb;
  unsigned short* stV1b = stcatb + (size_t)8000 * 128;
  unsigned short* stC1b = stcatb + (size_t)11000 * 128;
  unsigned short* stA0b = stcatb + (size_t)12500 * 128;
  (void)ws_size; (void)in_sizes; (void)n_in; (void)out_size;

  dim3 blk(256);
  const size_t giOff[5] = {0, 8000, 14000, 22000, 25000};

  // --- 1. batched f32->bf16 conversion ---
  CvtArgs ca{};
  int nseg = 0, totblk = 0;
  auto addseg = [&](const float* src, unsigned short* dst, int n) {
    ca.seg[nseg].src = src; ca.seg[nseg].dst = dst; ca.seg[nseg].n = n;
    ca.seg[nseg].nblk = (n + 1023) / 1024; totblk += ca.seg[nseg].nblk; ++nseg;
  };
  addseg(feat_P, featPb, 8000 * 128);
  addseg(feat_V, featVb, 3000 * 128);
  addseg(feat_C, featCb, 1500 * 128);
  addseg(feat_A, featAb, 6000 * 128);
  addseg(W1, W1b, 128 * 128);
  addseg(L00W, L00Wb, 1500 * 128);
  addseg(L01W, L01Wb, 1500 * 128);
  addseg(L10W, L10Wb, 1500 * 128);
  addseg(L11W, L11Wb, 1500 * 128);
  addseg(L12W, L12Wb, 1500 * 128);
  addseg(g0_Wih, g0Wihb, 384 * 128);
  addseg(g0_Whh, g0Whhb, 384 * 128);
  addseg(g1_Wih, g1Wihb, 384 * 128);
  addseg(g1_Whh, g1Whhb, 384 * 128);
  addseg(rel_emb, relb, 12 * 128);
  ca.nseg = nseg;
  hipLaunchKernelGGL(convert_bf16_many, dim3(totblk), blk, 0, stream, ca);

  // --- 2. static GEMMs: self(bf16) + 5x gi(bf16) + stage-0/2 logits(bf16) ---
  {
    GSegs gs{};
    int nb = 0, k = 0;
    auto add = [&](const unsigned short* X, const unsigned short* W, const float* bias,
                   unsigned short* Cb, int N, int O) {
      int xb = (N + 127) / 128, yb = (O + 63) / 64;
      gs.s[k] = GSeg{X, W, bias, nullptr, Cb, N, O, nb, xb};
      nb += xb * yb; ++k;
    };
    add(featb,  W1b,    b1,     selfbB,               18500, 128);
    add(featPb, g0Wihb, g0_bih, gib + giOff[0] * 384, 8000, 384);
    add(featAb, g0Wihb, g0_bih, gib + giOff[1] * 384, 6000, 384);
    add(featPb, g1Wihb, g1_bih, gib + giOff[2] * 384, 8000, 384);
    add(featVb, g1Wihb, g1_bih, gib + giOff[3] * 384, 3000, 384);
    add(featCb, g1Wihb, g1_bih, gib + giOff[4] * 384, 1500, 384);
    add(featVb, L00Wb,  L00b,   lg0b,                 3000, 1500);
    add(featAb, L10Wb,  L10b,   lg2b,                 6000, 1500);
    gs.nseg = k;
    hipLaunchKernelGGL(gemm_bf16_gseg, dim3(nb), blk, 0, stream, gs);
  }

  // --- 3. rowops stages 0+2 (bf16 logits, bf16 srcs) ---
  hipLaunchKernelGGL(rowops2b, dim3((9000 * 64 + 255) / 256), blk, 0, stream,
                     (const unsigned*)lg0b, clsV, (const unsigned*)featVb, scaled0, cebuf + 0 * 8000, 3000,
                     (const unsigned*)lg2b, clsA, (const unsigned*)featAb, scaled2, cebuf + 2 * 8000, 6000);
  // --- 4. spmv stages 0+2 ---
  hipLaunchKernelGGL(spmv_scan2, dim3(16000), blk, 0, stream,
                     adj00, scaled0, h0b, 8000, 3000,
                     adj10, scaled2, h2b, 6000);
  // --- 5. gh_gru stages 0+2 -> stP0b, stP1b ---
  hipLaunchKernelGGL(gh_gru2, dim3(500), blk, 0, stream,
                     h0b, g0Whhb, g0_bhh, gib + giOff[0] * 384, stP0b, 8000, 250,
                     h2b, g1Whhb, g1_bhh, gib + giOff[2] * 384, stP1b, 8000);
  // --- 6. logits stages 1+3 (bf16 out) ---
  {
    GSegs gs{};
    gs.s[0] = GSeg{stP0b, L01Wb, L01b, nullptr, lg1b, 8000, 1500, 0,    63};
    gs.s[1] = GSeg{stP1b, L11Wb, L11b, nullptr, lg3b, 8000, 1500, 1512, 63};
    gs.nseg = 2;
    hipLaunchKernelGGL(gemm_bf16_gseg, dim3(3024), blk, 0, stream, gs);
  }
  // --- 7. rowops stages 1+3 (paired; clsP read once) ---
  hipLaunchKernelGGL(rowops_pairb, dim3((8000 * 64 + 255) / 256), blk, 0, stream,
                     (const unsigned*)lg1b, (const unsigned*)lg3b, clsP,
                     (const unsigned*)stP0b, (const unsigned*)stP1b,
                     scaled1, scaled3, cebuf + 1 * 8000, cebuf + 3 * 8000, 8000);
  // --- 8. spmv stages 1+3 ---
  hipLaunchKernelGGL(spmv_scan2, dim3(9000), blk, 0, stream,
                     adj01, scaled1, h1b, 6000, 8000,
                     adj11, scaled3, h3b, 8000);
  // --- 9. gh_gru stages 1+3 -> stA0b, stV1b ---
  hipLaunchKernelGGL(gh_gru2, dim3(188 + 94), blk, 0, stream,
                     h1b, g0Whhb, g0_bhh, gib + giOff[1] * 384, stA0b, 6000, 188,
                     h3b, g1Whhb, g1_bhh, gib + giOff[3] * 384, stV1b, 3000);
  // --- 10-13. stage 4 ---
  {
    GSegs gs{};
    gs.s[0] = GSeg{stV1b, L12Wb, L12b, nullptr, lg1b, 3000, 1500, 0, 24};
    gs.nseg = 1;
    hipLaunchKernelGGL(gemm_bf16_gseg, dim3(24 * 24), blk, 0, stream, gs);
  }
  hipLaunchKernelGGL(rowops1b, dim3((3000 * 64 + 255) / 256), blk, 0, stream,
                     (const unsigned*)lg1b, clsV, (const unsigned*)stV1b,
                     scaled4, cebuf + 4 * 8000, 3000);
  hipLaunchKernelGGL(spmv_scan, dim3(1500), blk, 0, stream, adj12, scaled4, h4b, 1500, 3000);
  hipLaunchKernelGGL(gh_gru, dim3(47), blk, 0, stream,
                     h4b, g1Whhb, g1_bhh, gib + giOff[4] * 384, stC1b, 1500);

  // --- 14-16. fuse pipeline (bf16 e0/e1) ---
  hipLaunchKernelGGL(fuse_scores_all, dim3((18500 + 3) / 4), blk, 0, stream,
                     (const unsigned*)selfbB, (const unsigned*)stcatb, W2, b2, W3, b3, s0b, s1b);
  hipLaunchKernelGGL(denom4, dim3(4), dim3(1024), 0, stream, s0b, s1b, den);
  hipLaunchKernelGGL(fuse_emb_all, dim3((18500 * 64 + 768 + 255) / 256), blk, 0, stream,
                     (const unsigned*)selfbB, (const unsigned*)stcatb, s0b, s1b, den, rel_emb, fe, feb, rel_out);

  // --- 17. edges ---
  hipLaunchKernelGGL(edge_both, dim3(2048), blk, 0, stream, u_d, u_s, feb, relb, partial, 150000);

  // --- 18. final ---
  hipLaunchKernelGGL(final_reduce, dim3(1), dim3(1024), 0, stream, partial, cebuf, out);
}

// Round 14
// 486.800 us; speedup vs baseline: 6.0431x; 1.0071x over previous
//
#include <hip/hip_runtime.h>
#include <cstdint>
#include <cstddef>

#define DEV_INLINE __device__ __forceinline__

typedef __attribute__((ext_vector_type(8))) short bf16x8;
typedef __attribute__((ext_vector_type(16))) float f32x16;
struct __align__(8) US4 { unsigned short u[4]; };

DEV_INLINE unsigned short f2bf(float x) {
  unsigned u = __float_as_uint(x);
  return (unsigned short)((u + 0x7FFFu + ((u >> 16) & 1u)) >> 16);
}
DEV_INLINE float bf2f(unsigned short u) { return __uint_as_float(((unsigned)u) << 16); }
DEV_INLINE float2 bfpair(unsigned v) {
  return make_float2(__uint_as_float(v << 16), __uint_as_float(v & 0xFFFF0000u));
}
DEV_INLINE unsigned packbf(float a, float b) {
  return (unsigned)f2bf(a) | ((unsigned)f2bf(b) << 16);
}
DEV_INLINE float ftanh(float x) {
  float e = __expf(2.0f * x);
  return 1.0f - 2.0f / (e + 1.0f);
}
DEV_INLINE float softplus_neg(float x) {
  return (x >= 0.f) ? log1pf(__expf(-x)) : (-x + log1pf(__expf(x)));
}

// ---------------------------------------------------------------------------
// Batched f32 -> bf16 conversion
// ---------------------------------------------------------------------------
struct CvtSeg { const float* src; unsigned short* dst; int n; int nblk; };
struct CvtArgs { CvtSeg seg[16]; int nseg; };

__global__ __launch_bounds__(256) void convert_bf16_many(CvtArgs args) {
  int b = blockIdx.x;
  int s = 0;
  while (s < args.nseg && b >= args.seg[s].nblk) { b -= args.seg[s].nblk; ++s; }
  if (s >= args.nseg) return;
  int base = b * 1024 + threadIdx.x * 4;
  if (base >= args.seg[s].n) return;
  float4 v = *reinterpret_cast<const float4*>(args.seg[s].src + base);
  US4 o;
  o.u[0] = f2bf(v.x); o.u[1] = f2bf(v.y); o.u[2] = f2bf(v.z); o.u[3] = f2bf(v.w);
  *reinterpret_cast<US4*>(args.seg[s].dst + base) = o;
}

// ---------------------------------------------------------------------------
// bf16 MFMA GEMM: C = X @ W^T + bias; per-seg f32 (C) or bf16 (Cb) output.
// ---------------------------------------------------------------------------
struct GSeg { const unsigned short* X; const unsigned short* W; const float* bias;
              float* C; unsigned short* Cb; int N; int O; int blk0; int xblk; };
struct GSegs { GSeg s[8]; int nseg; };

__global__ __launch_bounds__(256) void gemm_bf16_gseg(GSegs gs) {
  __shared__ __align__(16) unsigned short Xs[128 * 128];
  __shared__ __align__(16) unsigned short Ws[64 * 128];
  int bx = blockIdx.x;
  int si = 0;
  while (si + 1 < gs.nseg && bx >= gs.s[si + 1].blk0) ++si;
  const GSeg& g = gs.s[si];
  int b = bx - g.blk0;
  int bm = (b % g.xblk) * 128;
  int bn = (b / g.xblk) * 64;
  const int tid = threadIdx.x;

#pragma unroll
  for (int i = 0; i < 8; ++i) {
    int s = tid + 256 * i;
    int row = s >> 4, c16 = s & 15;
    uint4 v = make_uint4(0, 0, 0, 0);
    int gr = bm + row;
    if (gr < g.N) v = *reinterpret_cast<const uint4*>(g.X + (size_t)gr * 128 + c16 * 8);
    *reinterpret_cast<uint4*>(&Xs[(row * 16 + (c16 ^ (row & 7))) * 8]) = v;
  }
#pragma unroll
  for (int i = 0; i < 4; ++i) {
    int s = tid + 256 * i;
    int row = s >> 4, c16 = s & 15;
    uint4 v = make_uint4(0, 0, 0, 0);
    int gw = bn + row;
    if (gw < g.O) v = *reinterpret_cast<const uint4*>(g.W + (size_t)gw * 128 + c16 * 8);
    *reinterpret_cast<uint4*>(&Ws[(row * 16 + (c16 ^ (row & 7))) * 8]) = v;
  }
  __syncthreads();

  const int wave = tid >> 6, lane = tid & 63;
  const int l31 = lane & 31, lhi = lane >> 5;

  f32x16 acc0, acc1;
#pragma unroll
  for (int i = 0; i < 16; ++i) { acc0[i] = 0.f; acc1[i] = 0.f; }
  const int ar = wave * 32 + l31;
#pragma unroll
  for (int ks = 0; ks < 8; ++ks) {
    int c16 = ks * 2 + lhi;
    bf16x8 a  = *reinterpret_cast<const bf16x8*>(&Xs[(ar * 16 + (c16 ^ (ar & 7))) * 8]);
    bf16x8 b0 = *reinterpret_cast<const bf16x8*>(&Ws[(l31 * 16 + (c16 ^ (l31 & 7))) * 8]);
    int br1 = 32 + l31;
    bf16x8 b1 = *reinterpret_cast<const bf16x8*>(&Ws[(br1 * 16 + (c16 ^ (br1 & 7))) * 8]);
    acc0 = __builtin_amdgcn_mfma_f32_32x32x16_bf16(a, b0, acc0, 0, 0, 0);
    acc1 = __builtin_amdgcn_mfma_f32_32x32x16_bf16(a, b1, acc1, 0, 0, 0);
  }

  if (g.Cb) {
#pragma unroll
    for (int reg = 0; reg < 16; ++reg) {
      int r = bm + wave * 32 + (reg & 3) + 8 * (reg >> 2) + 4 * lhi;
      if (r < g.N) {
        int c0 = bn + l31;
        if (c0 < g.O) g.Cb[(size_t)r * g.O + c0] = f2bf(acc0[reg] + g.bias[c0]);
        int c1 = bn + 32 + l31;
        if (c1 < g.O) g.Cb[(size_t)r * g.O + c1] = f2bf(acc1[reg] + g.bias[c1]);
      }
    }
  } else {
#pragma unroll
    for (int reg = 0; reg < 16; ++reg) {
      int r = bm + wave * 32 + (reg & 3) + 8 * (reg >> 2) + 4 * lhi;
      if (r < g.N) {
        int c0 = bn + l31;
        if (c0 < g.O) g.C[(size_t)r * g.O + c0] = acc0[reg] + g.bias[c0];
        int c1 = bn + 32 + l31;
        if (c1 < g.O) g.C[(size_t)r * g.O + c1] = acc1[reg] + g.bias[c1];
      }
    }
  }
}

// ---------------------------------------------------------------------------
// Sparse row scan: block (4 waves) per row; bf16 X (packed pairs) -> bf16 H.
// Lane l owns dims {2l, 2l+1}: ONE uint gather per nonzero per lane.
// ---------------------------------------------------------------------------
DEV_INLINE void spmv_body_b(const float* __restrict__ A, const unsigned* __restrict__ Xs,
                            unsigned* __restrict__ Hb, int row, int K,
                            float (*red)[128])
{
  int tid = threadIdx.x, wave = tid >> 6, lane = tid & 63;
  const float4* Arow = reinterpret_cast<const float4*>(A + (size_t)row * K);
  int K4 = K >> 2;
  float acc0 = 0.f, acc1 = 0.f;
  int base = wave * 64;
  int q = base + lane;
  float4 a = (base < K4 && q < K4) ? Arow[q] : make_float4(0.f, 0.f, 0.f, 0.f);
  for (; base < K4; base += 256) {
    int nb = base + 256;
    int nq = nb + lane;
    float4 an = (nb < K4 && nq < K4) ? Arow[nq] : make_float4(0.f, 0.f, 0.f, 0.f);
#pragma unroll
    for (int c = 0; c < 4; ++c) {
      float av = (c == 0) ? a.x : (c == 1) ? a.y : (c == 2) ? a.z : a.w;
      unsigned long long mm = __ballot(av != 0.f);
      while (mm) {
        int b = __builtin_ctzll(mm);
        mm &= mm - 1;
        float v = __shfl(av, b);
        int jj = (base + b) * 4 + c;
        float2 p = bfpair(Xs[(size_t)jj * 64 + lane]);
        acc0 += v * p.x;
        acc1 += v * p.y;
      }
    }
    a = an;
  }
  red[wave][lane] = acc0;
  red[wave][lane + 64] = acc1;
  __syncthreads();
  if (wave == 0) {
    float r0 = red[0][lane] + red[1][lane] + red[2][lane] + red[3][lane];
    float r1 = red[0][lane + 64] + red[1][lane + 64] + red[2][lane + 64] + red[3][lane + 64];
    Hb[(size_t)row * 64 + lane] = packbf(r0, r1);   // dims {2l, 2l+1}, natural order
  }
}

__global__ __launch_bounds__(256) void spmv_scan(
    const float* __restrict__ A, const unsigned* __restrict__ Xs,
    unsigned* __restrict__ Hb, int M, int K)
{
  __shared__ float red[4][128];
  spmv_body_b(A, Xs, Hb, blockIdx.x, K, red);
}

__global__ __launch_bounds__(256) void spmv_scan2(
    const float* __restrict__ A0, const unsigned* __restrict__ X0,
    unsigned* __restrict__ H0b, int M0, int K0,
    const float* __restrict__ A1, const unsigned* __restrict__ X1,
    unsigned* __restrict__ H1b, int K1)
{
  __shared__ float red[4][128];
  if ((int)blockIdx.x < M0) spmv_body_b(A0, X0, H0b, blockIdx.x, K0, red);
  else                      spmv_body_b(A1, X1, H1b, blockIdx.x - M0, K1, red);
}

// ---------------------------------------------------------------------------
// Fused gh-GEMM + GRU (32-row tile; bf16 H/gi; bf16 state out only)
// ---------------------------------------------------------------------------
DEV_INLINE void ghgru_body_b(
    const unsigned short* __restrict__ Hb, const unsigned short* __restrict__ Whhb,
    const float* __restrict__ bhh, const unsigned short* __restrict__ gi,
    unsigned short* __restrict__ outb, int M, int bm, unsigned short* As)
{
  const int tid = threadIdx.x;
#pragma unroll
  for (int i = 0; i < 2; ++i) {
    int s = tid + 256 * i;
    int row = s >> 4, c16 = s & 15;
    uint4 v = make_uint4(0, 0, 0, 0);
    int gr = bm + row;
    if (gr < M) v = *reinterpret_cast<const uint4*>(Hb + (size_t)gr * 128 + c16 * 8);
    *reinterpret_cast<uint4*>(&As[(row * 16 + (c16 ^ (row & 7))) * 8]) = v;
  }
  __syncthreads();

  const int wave = tid >> 6, lane = tid & 63;
  const int l31 = lane & 31, lhi = lane >> 5;
  const int d = wave * 32 + l31;

  f32x16 ar, az, an;
#pragma unroll
  for (int i = 0; i < 16; ++i) { ar[i] = 0.f; az[i] = 0.f; an[i] = 0.f; }

#pragma unroll
  for (int ks = 0; ks < 8; ++ks) {
    int c16 = ks * 2 + lhi;
    bf16x8 a = *reinterpret_cast<const bf16x8*>(&As[(l31 * 16 + (c16 ^ (l31 & 7))) * 8]);
    const unsigned short* wb = Whhb + (size_t)c16 * 8;
    bf16x8 br = *reinterpret_cast<const bf16x8*>(wb + (size_t)d * 128);
    bf16x8 bz = *reinterpret_cast<const bf16x8*>(wb + (size_t)(128 + d) * 128);
    bf16x8 bn = *reinterpret_cast<const bf16x8*>(wb + (size_t)(256 + d) * 128);
    ar = __builtin_amdgcn_mfma_f32_32x32x16_bf16(a, br, ar, 0, 0, 0);
    az = __builtin_amdgcn_mfma_f32_32x32x16_bf16(a, bz, az, 0, 0, 0);
    an = __builtin_amdgcn_mfma_f32_32x32x16_bf16(a, bn, an, 0, 0, 0);
  }

  const float b_r = bhh[d], b_z = bhh[128 + d], b_n = bhh[256 + d];
#pragma unroll
  for (int reg = 0; reg < 16; ++reg) {
    int rowl = (reg & 3) + 8 * (reg >> 2) + 4 * lhi;
    int r = bm + rowl;
    if (r < M) {
      const unsigned short* gir = gi + (size_t)r * 384;
      float rr = 1.f / (1.f + __expf(-(bf2f(gir[d]) + ar[reg] + b_r)));
      float zz = 1.f / (1.f + __expf(-(bf2f(gir[128 + d]) + az[reg] + b_z)));
      float nn = ftanh(bf2f(gir[256 + d]) + rr * (an[reg] + b_n));
      float h = bf2f(As[(rowl * 16 + ((d >> 3) ^ (rowl & 7))) * 8 + (d & 7)]);
      float o = (1.f - zz) * nn + zz * h;
      outb[(size_t)r * 128 + d] = f2bf(o);
    }
  }
}

__global__ __launch_bounds__(256) void gh_gru(
    const unsigned short* __restrict__ Hb, const unsigned short* __restrict__ Whhb,
    const float* __restrict__ bhh, const unsigned short* __restrict__ gi,
    unsigned short* __restrict__ outb, int M)
{
  __shared__ __align__(16) unsigned short As[32 * 128];
  ghgru_body_b(Hb, Whhb, bhh, gi, outb, M, blockIdx.x * 32, As);
}

__global__ __launch_bounds__(256) void gh_gru2(
    const unsigned short* Hb0, const unsigned short* Whh0, const float* bhh0,
    const unsigned short* gi0, unsigned short* outb0, int M0, int nblk0,
    const unsigned short* Hb1, const unsigned short* Whh1, const float* bhh1,
    const unsigned short* gi1, unsigned short* outb1, int M1)
{
  __shared__ __align__(16) unsigned short As[32 * 128];
  if ((int)blockIdx.x < nblk0)
    ghgru_body_b(Hb0, Whh0, bhh0, gi0, outb0, M0, blockIdx.x * 32, As);
  else
    ghgru_body_b(Hb1, Whh1, bhh1, gi1, outb1, M1, (blockIdx.x - nblk0) * 32, As);
}

// ---------------------------------------------------------------------------
// Wave-per-row softmax / CE / tcp; bf16 logits + bf16 src; bf16 scaled out.
// ---------------------------------------------------------------------------
DEV_INLINE void rowops_body_b(int lane, const unsigned* __restrict__ lrb,
                              const float2* __restrict__ cr2,
                              const unsigned* __restrict__ srcb,
                              unsigned* __restrict__ scb, float* __restrict__ cep)
{
  float2 e[12];
  float m = -3.4e38f;
#pragma unroll
  for (int k = 0; k < 12; ++k) {
    int idx = k * 64 + lane;
    if (idx < 750) {
      e[k] = bfpair(lrb[idx]);
      m = fmaxf(m, fmaxf(e[k].x, e[k].y));
    } else {
      e[k] = make_float2(-3.4e38f, -3.4e38f);
    }
  }
#pragma unroll
  for (int o = 1; o < 64; o <<= 1) m = fmaxf(m, __shfl_xor(m, o));
  float z = 0.f;
#pragma unroll
  for (int k = 0; k < 12; ++k) {
    e[k].x = __expf(e[k].x - m); e[k].y = __expf(e[k].y - m);
    z += e[k].x + e[k].y;
  }
#pragma unroll
  for (int o = 1; o < 64; o <<= 1) z += __shfl_xor(z, o);
  float invZ1 = 1.0f / z;
  float m2 = invZ1;
  float t = 0.f, ls = 0.f, z2 = 0.f;
#pragma unroll
  for (int k = 0; k < 12; ++k) {
    int idx = k * 64 + lane;
    if (idx < 750) {
      float2 c = cr2[idx];
      float px = e[k].x * invZ1, py = e[k].y * invZ1;
      t  += c.x * px + c.y * py;
      ls += c.x + c.y;
      z2 += __expf(px - m2) + __expf(py - m2);
    }
  }
#pragma unroll
  for (int o = 1; o < 64; o <<= 1) {
    t += __shfl_xor(t, o); ls += __shfl_xor(ls, o); z2 += __shfl_xor(z2, o);
  }
  if (lane == 0) *cep = t - ls * (m2 + logf(z2));
  float2 sv = bfpair(srcb[lane]);
  scb[lane] = packbf(t * sv.x, t * sv.y);
}

__global__ __launch_bounds__(256) void rowops2b(
    const unsigned* lgA, const float* clsA_, const unsigned* srcA, unsigned* scA, float* ceA, int nA,
    const unsigned* lgB, const float* clsB_, const unsigned* srcB, unsigned* scB, float* ceB, int nB)
{
  int gw = (blockIdx.x * 256 + threadIdx.x) >> 6;
  if (gw >= nA + nB) return;
  int lane = threadIdx.x & 63;
  if (gw < nA) {
    rowops_body_b(lane, lgA + (size_t)gw * 750,
                  reinterpret_cast<const float2*>(clsA_ + (size_t)gw * 1500),
                  srcA + (size_t)gw * 64, scA + (size_t)gw * 64, ceA + gw);
  } else {
    int r = gw - nA;
    rowops_body_b(lane, lgB + (size_t)r * 750,
                  reinterpret_cast<const float2*>(clsB_ + (size_t)r * 1500),
                  srcB + (size_t)r * 64, scB + (size_t)r * 64, ceB + r);
  }
}

__global__ __launch_bounds__(256) void rowops1b(
    const unsigned* lg, const float* cls, const unsigned* src, unsigned* sc, float* ce, int n)
{
  int gw = (blockIdx.x * 256 + threadIdx.x) >> 6;
  if (gw >= n) return;
  int lane = threadIdx.x & 63;
  rowops_body_b(lane, lg + (size_t)gw * 750,
                reinterpret_cast<const float2*>(cls + (size_t)gw * 1500),
                src + (size_t)gw * 64, sc + (size_t)gw * 64, ce + gw);
}

// stages 1+3 share clsP: one wave handles row r of BOTH stages; cls read once.
__global__ __launch_bounds__(256) void rowops_pairb(
    const unsigned* lg1, const unsigned* lg3, const float* clsP,
    const unsigned* src1, const unsigned* src3,
    unsigned* sc1, unsigned* sc3, float* ce1, float* ce3, int n)
{
  int gw = (blockIdx.x * 256 + threadIdx.x) >> 6;
  if (gw >= n) return;
  int lane = threadIdx.x & 63;
  const unsigned* l1 = lg1 + (size_t)gw * 750;
  const unsigned* l3 = lg3 + (size_t)gw * 750;
  const float2* cr2 = reinterpret_cast<const float2*>(clsP + (size_t)gw * 1500);

  float2 e1[12], e3[12];
  float m1 = -3.4e38f, m3 = -3.4e38f;
#pragma unroll
  for (int k = 0; k < 12; ++k) {
    int idx = k * 64 + lane;
    if (idx < 750) {
      e1[k] = bfpair(l1[idx]);
      e3[k] = bfpair(l3[idx]);
      m1 = fmaxf(m1, fmaxf(e1[k].x, e1[k].y));
      m3 = fmaxf(m3, fmaxf(e3[k].x, e3[k].y));
    } else {
      e1[k] = make_float2(-3.4e38f, -3.4e38f);
      e3[k] = make_float2(-3.4e38f, -3.4e38f);
    }
  }
#pragma unroll
  for (int o = 1; o < 64; o <<= 1) {
    m1 = fmaxf(m1, __shfl_xor(m1, o));
    m3 = fmaxf(m3, __shfl_xor(m3, o));
  }
  float z1 = 0.f, z3 = 0.f;
#pragma unroll
  for (int k = 0; k < 12; ++k) {
    e1[k].x = __expf(e1[k].x - m1); e1[k].y = __expf(e1[k].y - m1);
    e3[k].x = __expf(e3[k].x - m3); e3[k].y = __expf(e3[k].y - m3);
    z1 += e1[k].x + e1[k].y;
    z3 += e3[k].x + e3[k].y;
  }
#pragma unroll
  for (int o = 1; o < 64; o <<= 1) { z1 += __shfl_xor(z1, o); z3 += __shfl_xor(z3, o); }
  float iZ1 = 1.0f / z1, iZ3 = 1.0f / z3;
  float q1 = iZ1, q3 = iZ3;
  float t1 = 0.f, t3 = 0.f, ls = 0.f, w1 = 0.f, w3 = 0.f;
#pragma unroll
  for (int k = 0; k < 12; ++k) {
    int idx = k * 64 + lane;
    if (idx < 750) {
      float2 c = cr2[idx];
      float p1x = e1[k].x * iZ1, p1y = e1[k].y * iZ1;
      float p3x = e3[k].x * iZ3, p3y = e3[k].y * iZ3;
      t1 += c.x * p1x + c.y * p1y;
      t3 += c.x * p3x + c.y * p3y;
      ls += c.x + c.y;
      w1 += __expf(p1x - q1) + __expf(p1y - q1);
      w3 += __expf(p3x - q3) + __expf(p3y - q3);
    }
  }
#pragma unroll
  for (int o = 1; o < 64; o <<= 1) {
    t1 += __shfl_xor(t1, o); t3 += __shfl_xor(t3, o); ls += __shfl_xor(ls, o);
    w1 += __shfl_xor(w1, o); w3 += __shfl_xor(w3, o);
  }
  if (lane == 0) {
    ce1[gw] = t1 - ls * (q1 + logf(w1));
    ce3[gw] = t3 - ls * (q3 + logf(w3));
  }
  float2 s1 = bfpair(src1[(size_t)gw * 64 + lane]);
  float2 s3 = bfpair(src3[(size_t)gw * 64 + lane]);
  sc1[(size_t)gw * 64 + lane] = packbf(t1 * s1.x, t1 * s1.y);
  sc3[(size_t)gw * 64 + lane] = packbf(t3 * s3.x, t3 * s3.y);
}

// ---------------------------------------------------------------------------
// Fuse pipeline (bf16 e0/e1)
// ---------------------------------------------------------------------------
__global__ __launch_bounds__(256) void fuse_scores_all(
    const unsigned* __restrict__ e0, const unsigned* __restrict__ e1,
    const float* __restrict__ W2, const float* __restrict__ b2,
    const float* __restrict__ W3, const float* __restrict__ b3,
    float* __restrict__ s0, float* __restrict__ s1)
{
  int lane = threadIdx.x & 63;
  int row = (blockIdx.x * 256 + threadIdx.x) >> 6;
  if (row >= 18500) return;
  float2 w2 = *reinterpret_cast<const float2*>(W2 + lane * 2);
  float2 w3 = *reinterpret_cast<const float2*>(W3 + lane * 2);
  float2 v0 = bfpair(e0[(size_t)row * 64 + lane]);
  float2 v1 = bfpair(e1[(size_t)row * 64 + lane]);
  float a0 = v0.x * w2.x + v0.y * w2.y;
  float a1 = v1.x * w3.x + v1.y * w3.y;
#pragma unroll
  for (int o = 32; o > 0; o >>= 1) { a0 += __shfl_down(a0, o); a1 += __shfl_down(a1, o); }
  if (lane == 0) {
    s0[row] = fmaxf(a0 + b2[0], 0.f);
    s1[row] = fmaxf(a1 + b3[0], 0.f);
  }
}

__global__ __launch_bounds__(1024) void denom4(
    const float* __restrict__ s0, const float* __restrict__ s1,
    float* __restrict__ den)
{
  __shared__ float red[1024];
  const int ns[4]   = {8000, 3000, 1500, 6000};
  const int offs[4] = {0, 8000, 11000, 12500};
  int b = blockIdx.x;
  int n = ns[b];
  const float* p0 = s0 + offs[b];
  const float* p1 = s1 + offs[b];
  int tid = threadIdx.x;
  float m = -3.4e38f;
  for (int i = tid; i < n; i += 1024) m = fmaxf(m, p0[i]);
  red[tid] = m; __syncthreads();
  for (int s = 512; s > 0; s >>= 1) { if (tid < s) red[tid] = fmaxf(red[tid], red[tid + s]); __syncthreads(); }
  float m0 = red[0]; __syncthreads();
  float z = 0.f;
  for (int i = tid; i < n; i += 1024) z += __expf(p0[i] - m0);
  red[tid] = z; __syncthreads();
  for (int s = 512; s > 0; s >>= 1) { if (tid < s) red[tid] += red[tid + s]; __syncthreads(); }
  float Z0 = red[0]; __syncthreads();
  m = -3.4e38f;
  for (int i = tid; i < n; i += 1024) m = fmaxf(m, p1[i]);
  red[tid] = m; __syncthreads();
  for (int s = 512; s > 0; s >>= 1) { if (tid < s) red[tid] = fmaxf(red[tid], red[tid + s]); __syncthreads(); }
  float m1 = red[0]; __syncthreads();
  z = 0.f;
  for (int i = tid; i < n; i += 1024) z += __expf(p1[i] - m1);
  red[tid] = z; __syncthreads();
  for (int s = 512; s > 0; s >>= 1) { if (tid < s) red[tid] += red[tid + s]; __syncthreads(); }
  if (tid == 0) { den[b * 4] = m0; den[b * 4 + 1] = Z0; den[b * 4 + 2] = m1; den[b * 4 + 3] = red[0]; }
}

__global__ __launch_bounds__(256) void fuse_emb_all(
    const unsigned* __restrict__ e0, const unsigned* __restrict__ e1,
    const float* __restrict__ s0, const float* __restrict__ s1,
    const float* __restrict__ den, const float* __restrict__ rel,
    float* __restrict__ fe, unsigned short* __restrict__ feb,
    float* __restrict__ rel_out)
{
  int t = blockIdx.x * 256 + threadIdx.x;
  const int tot2 = 18500 * 64;
  if (t < tot2) {
    int idx = t * 2;
    int row = idx >> 7;
    int e = (row < 8000) ? 0 : (row < 11000) ? 1 : (row < 12500) ? 2 : 3;
    float a0 = __expf(s0[row] - den[e * 4]) / den[e * 4 + 1];
    float a1 = __expf(s1[row] - den[e * 4 + 2]) / den[e * 4 + 3];
    float2 v0 = bfpair(e0[t]);
    float2 v1 = bfpair(e1[t]);
    float r0 = fmaxf(a0 * v0.x + a1 * v1.x, 0.f);
    float r1 = fmaxf(a0 * v0.y + a1 * v1.y, 0.f);
    *reinterpret_cast<float2*>(fe + idx) = make_float2(r0, r1);
    *reinterpret_cast<unsigned*>(feb + idx) = packbf(r0, r1);
  } else if (t < tot2 + 768) {
    int k = (t - tot2) * 2;
    *reinterpret_cast<float2*>(rel_out + k) = *reinterpret_cast<const float2*>(rel + k);
  }
}

// ---------------------------------------------------------------------------
// Edge losses: half-wave per edge, fast tanh, 2-deep gather pipeline.
// ---------------------------------------------------------------------------
__global__ __launch_bounds__(256) void edge_both(
    const int* __restrict__ ud, const int* __restrict__ us,
    const unsigned short* __restrict__ feb, const unsigned short* __restrict__ relb,
    float* __restrict__ partial, int En)
{
  const int tid = threadIdx.x;
  const int lane = tid & 63;
  const int l = lane & 31, h = lane >> 5;
  const int wid = tid >> 6;
  bool is_d = (blockIdx.x < 1024);
  int bb = is_d ? blockIdx.x : blockIdx.x - 1024;
  int e = (bb * 4 + wid) * 2 + h;
  const int ns = 1024 * 4 * 2;
  float acc = 0.f;
  if (is_d) {
    int4 ei = (e < En) ? *reinterpret_cast<const int4*>(ud + (size_t)e * 4)
                       : make_int4(0, 0, 0, 0);
    uint2 av = reinterpret_cast<const uint2*>(feb + (size_t)ei.x * 128)[l];
    uint2 bv = reinterpret_cast<const uint2*>(feb + (size_t)ei.y * 128)[l];
    uint2 rv = reinterpret_cast<const uint2*>(relb + (size_t)ei.w * 128)[l];
    for (; e < En; e += ns) {
      int en = e + ns;
      int4 ein = (en < En) ? *reinterpret_cast<const int4*>(ud + (size_t)en * 4)
                           : make_int4(0, 0, 0, 0);
      uint2 avn = reinterpret_cast<const uint2*>(feb + (size_t)ein.x * 128)[l];
      uint2 bvn = reinterpret_cast<const uint2*>(feb + (size_t)ein.y * 128)[l];
      uint2 rvn = reinterpret_cast<const uint2*>(relb + (size_t)ein.w * 128)[l];
      float2 a0 = bfpair(av.x), a1 = bfpair(av.y);
      float2 b0 = bfpair(bv.x), b1 = bfpair(bv.y);
      float2 r0 = bfpair(rv.x), r1 = bfpair(rv.y);
      float d = r0.x * ftanh(a0.x + b0.x) + r0.y * ftanh(a0.y + b0.y)
              + r1.x * ftanh(a1.x + b1.x) + r1.y * ftanh(a1.y + b1.y);
#pragma unroll
      for (int o = 1; o < 32; o <<= 1) d += __shfl_xor(d, o);
      if (l == 0) acc += softplus_neg((float)ei.z * d);
      ei = ein; av = avn; bv = bvn; rv = rvn;
    }
  } else {
    int3 ei = make_int3(0, 0, 0);
    if (e < En) { ei.x = us[(size_t)e * 3]; ei.y = us[(size_t)e * 3 + 1]; ei.z = us[(size_t)e * 3 + 2]; }
    uint2 av = reinterpret_cast<const uint2*>(feb + (size_t)ei.x * 128)[l];
    uint2 bv = reinterpret_cast<const uint2*>(feb + (size_t)ei.y * 128)[l];
    for (; e < En; e += ns) {
      int en = e + ns;
      int3 ein = make_int3(0, 0, 0);
      if (en < En) { ein.x = us[(size_t)en * 3]; ein.y = us[(size_t)en * 3 + 1]; ein.z = us[(size_t)en * 3 + 2]; }
      uint2 avn = reinterpret_cast<const uint2*>(feb + (size_t)ein.x * 128)[l];
      uint2 bvn = reinterpret_cast<const uint2*>(feb + (size_t)ein.y * 128)[l];
      float2 a0 = bfpair(av.x), a1 = bfpair(av.y);
      float2 b0 = bfpair(bv.x), b1 = bfpair(bv.y);
      float d = a0.x * b0.x + a0.y * b0.y + a1.x * b1.x + a1.y * b1.y;
#pragma unroll
      for (int o = 1; o < 32; o <<= 1) d += __shfl_xor(d, o);
      if (l == 0) acc += softplus_neg((float)ei.z * d);
      ei = ein; av = avn; bv = bvn;
    }
  }
  __shared__ float red[8];
  if (l == 0) red[wid * 2 + h] = acc;
  __syncthreads();
  if (tid == 0) {
    float s = 0.f;
#pragma unroll
    for (int i = 0; i < 8; ++i) s += red[i];
    partial[blockIdx.x] = s;
  }
}

__global__ __launch_bounds__(1024) void final_reduce(
    const float* __restrict__ partial, const float* __restrict__ cebuf,
    float* __restrict__ out)
{
  __shared__ float red[1024];
  __shared__ float total;
  int tid = threadIdx.x;
  if (tid == 0) total = 0.f;
  __syncthreads();
  float a = partial[tid] + partial[tid + 1024];
  red[tid] = a; __syncthreads();
  for (int s = 512; s > 0; s >>= 1) { if (tid < s) red[tid] += red[tid + s]; __syncthreads(); }
  if (tid == 0) total += red[0];
  __syncthreads();
  const int ns[5] = {3000, 8000, 6000, 8000, 3000};
#pragma unroll
  for (int seg = 0; seg < 5; ++seg) {
    const float* v = cebuf + seg * 8000;
    float s = 0.f;
    for (int i = tid; i < ns[seg]; i += 1024) s += v[i];
    red[tid] = s; __syncthreads();
    for (int st = 512; st > 0; st >>= 1) { if (tid < st) red[tid] += red[tid + st]; __syncthreads(); }
    if (tid == 0) total -= red[0] / (float)ns[seg];
    __syncthreads();
  }
  if (tid == 0) out[0] = total;
}

// ---------------------------------------------------------------------------
extern "C" void kernel_launch(void* const* d_in, const int* in_sizes, int n_in,
                              void* d_out, int out_size, void* d_ws, size_t ws_size,
                              hipStream_t stream)
{
  const float* feat_P = (const float*)d_in[0];
  const float* feat_V = (const float*)d_in[1];
  const float* feat_C = (const float*)d_in[2];
  const float* feat_A = (const float*)d_in[3];
  const float* W1 = (const float*)d_in[4];
  const float* b1 = (const float*)d_in[5];
  const float* W2 = (const float*)d_in[6];
  const float* b2 = (const float*)d_in[7];
  const float* W3 = (const float*)d_in[8];
  const float* b3 = (const float*)d_in[9];
  const float* L00W = (const float*)d_in[10];
  const float* L00b = (const float*)d_in[11];
  const float* L01W = (const float*)d_in[12];
  const float* L01b = (const float*)d_in[13];
  const float* L10W = (const float*)d_in[14];
  const float* L10b = (const float*)d_in[15];
  const float* L11W = (const float*)d_in[16];
  const float* L11b = (const float*)d_in[17];
  const float* L12W = (const float*)d_in[18];
  const float* L12b = (const float*)d_in[19];
  const float* g0_Wih = (const float*)d_in[20];
  const float* g0_Whh = (const float*)d_in[21];
  const float* g0_bih = (const float*)d_in[22];
  const float* g0_bhh = (const float*)d_in[23];
  const float* g1_Wih = (const float*)d_in[24];
  const float* g1_Whh = (const float*)d_in[25];
  const float* g1_bih = (const float*)d_in[26];
  const float* g1_bhh = (const float*)d_in[27];
  const float* rel_emb = (const float*)d_in[28];
  const float* adj00 = (const float*)d_in[29];
  const float* adj01 = (const float*)d_in[30];
  const float* adj10 = (const float*)d_in[31];
  const float* adj11 = (const float*)d_in[32];
  const float* adj12 = (const float*)d_in[33];
  const float* clsA = (const float*)d_in[34];
  const float* clsP = (const float*)d_in[35];
  const float* clsV = (const float*)d_in[36];
  const int* u_s = (const int*)d_in[37];
  const int* u_d = (const int*)d_in[38];

  float* out = (float*)d_out;
  float* fe = out + 1;
  float* rel_out = out + 1 + 18500 * 128;

  float* ws = (float*)d_ws;
  size_t o = 0;
  auto alloc = [&](size_t n) { float* p = ws + o; o += n; return p; };
  float* cebuf   = alloc(5 * 8000);
  float* s0b = alloc(18500);
  float* s1b = alloc(18500);
  float* den = alloc(16);
  float* partial = alloc(2048);
  auto allocb = [&](size_t nelem) { unsigned short* p = (unsigned short*)(ws + o); o += (nelem + 1) / 2; return p; };
  unsigned short* featb  = allocb((size_t)18500 * 128);
  unsigned short* selfbB = allocb((size_t)18500 * 128);
  unsigned short* stcatb = allocb((size_t)18500 * 128);   // P0|V1|C1|A0
  unsigned short* stP1b  = allocb((size_t)8000 * 128);
  unsigned short* feb    = allocb((size_t)18500 * 128);
  unsigned short* scaled0 = allocb((size_t)3000 * 128);
  unsigned short* scaled1 = allocb((size_t)8000 * 128);
  unsigned short* scaled2 = allocb((size_t)6000 * 128);
  unsigned short* scaled3 = allocb((size_t)8000 * 128);
  unsigned short* scaled4 = allocb((size_t)3000 * 128);
  unsigned short* h0b    = allocb((size_t)8000 * 128);
  unsigned short* h2b    = allocb((size_t)8000 * 128);
  unsigned short* h1b    = allocb((size_t)6000 * 128);
  unsigned short* h3b    = allocb((size_t)3000 * 128);
  unsigned short* h4b    = allocb((size_t)1500 * 128);
  unsigned short* gib    = allocb((size_t)26500 * 384);
  unsigned short* lg0b   = allocb((size_t)3000 * 1500);
  unsigned short* lg2b   = allocb((size_t)6000 * 1500);
  unsigned short* lg1b   = allocb((size_t)8000 * 1500);  // stage 1 (and 4 reuse)
  unsigned short* lg3b   = allocb((size_t)8000 * 1500);  // stage 3
  unsigned short* relb   = allocb(12 * 128);
  unsigned short* W1b = allocb(128 * 128);
  unsigned short* L00Wb = allocb(1500 * 128);
  unsigned short* L01Wb = allocb(1500 * 128);
  unsigned short* L10Wb = allocb(1500 * 128);
  unsigned short* L11Wb = allocb(1500 * 128);
  unsigned short* L12Wb = allocb(1500 * 128);
  unsigned short* g0Wihb = allocb(384 * 128);
  unsigned short* g0Whhb = allocb(384 * 128);
  unsigned short* g1Wihb = allocb(384 * 128);
  unsigned short* g1Whhb = allocb(384 * 128);
  unsigned short* featPb = featb;
  unsigned short* featVb = featb + (size_t)8000 * 128;
  unsigned short* featCb = featb + (size_t)11000 * 128;
  unsigned short* featAb = featb + (size_t)12500 * 128;
  unsigned short* stP0b = stcatb;
  unsigned short* stV1b = stcatb + (size_t)8000 * 128;
  unsigned short* stC1b = stcatb + (size_t)11000 * 128;
  unsigned short* stA0b = stcatb + (size_t)12500 * 128;
  (void)ws_size; (void)in_sizes; (void)n_in; (void)out_size;

  dim3 blk(256);
  const size_t giOff[5] = {0, 8000, 14000, 22000, 25000};

  // --- 1. batched f32->bf16 conversion ---
  CvtArgs ca{};
  int nseg = 0, totblk = 0;
  auto addseg = [&](const float* src, unsigned short* dst, int n) {
    ca.seg[nseg].src = src; ca.seg[nseg].dst = dst; ca.seg[nseg].n = n;
    ca.seg[nseg].nblk = (n + 1023) / 1024; totblk += ca.seg[nseg].nblk; ++nseg;
  };
  addseg(feat_P, featPb, 8000 * 128);
  addseg(feat_V, featVb, 3000 * 128);
  addseg(feat_C, featCb, 1500 * 128);
  addseg(feat_A, featAb, 6000 * 128);
  addseg(W1, W1b, 128 * 128);
  addseg(L00W, L00Wb, 1500 * 128);
  addseg(L01W, L01Wb, 1500 * 128);
  addseg(L10W, L10Wb, 1500 * 128);
  addseg(L11W, L11Wb, 1500 * 128);
  addseg(L12W, L12Wb, 1500 * 128);
  addseg(g0_Wih, g0Wihb, 384 * 128);
  addseg(g0_Whh, g0Whhb, 384 * 128);
  addseg(g1_Wih, g1Wihb, 384 * 128);
  addseg(g1_Whh, g1Whhb, 384 * 128);
  addseg(rel_emb, relb, 12 * 128);
  ca.nseg = nseg;
  hipLaunchKernelGGL(convert_bf16_many, dim3(totblk), blk, 0, stream, ca);

  // --- 2. static GEMMs: self(bf16) + 5x gi(bf16) + stage-0/2 logits(bf16) ---
  {
    GSegs gs{};
    int nb = 0, k = 0;
    auto add = [&](const unsigned short* X, const unsigned short* W, const float* bias,
                   unsigned short* Cb, int N, int O) {
      int xb = (N + 127) / 128, yb = (O + 63) / 64;
      gs.s[k] = GSeg{X, W, bias, nullptr, Cb, N, O, nb, xb};
      nb += xb * yb; ++k;
    };
    add(featb,  W1b,    b1,     selfbB,               18500, 128);
    add(featPb, g0Wihb, g0_bih, gib + giOff[0] * 384, 8000, 384);
    add(featAb, g0Wihb, g0_bih, gib + giOff[1] * 384, 6000, 384);
    add(featPb, g1Wihb, g1_bih, gib + giOff[2] * 384, 8000, 384);
    add(featVb, g1Wihb, g1_bih, gib + giOff[3] * 384, 3000, 384);
    add(featCb, g1Wihb, g1_bih, gib + giOff[4] * 384, 1500, 384);
    add(featVb, L00Wb,  L00b,   lg0b,                 3000, 1500);
    add(featAb, L10Wb,  L10b,   lg2b,                 6000, 1500);
    gs.nseg = k;
    hipLaunchKernelGGL(gemm_bf16_gseg, dim3(nb), blk, 0, stream, gs);
  }

  // --- 3. rowops stages 0+2 (bf16 logits/srcs -> bf16 scaled) ---
  hipLaunchKernelGGL(rowops2b, dim3((9000 * 64 + 255) / 256), blk, 0, stream,
                     (const unsigned*)lg0b, clsV, (const unsigned*)featVb,
                     (unsigned*)scaled0, cebuf + 0 * 8000, 3000,
                     (const unsigned*)lg2b, clsA, (const unsigned*)featAb,
                     (unsigned*)scaled2, cebuf + 2 * 8000, 6000);
  // --- 4. spmv stages 0+2 (bf16 gathers) ---
  hipLaunchKernelGGL(spmv_scan2, dim3(16000), blk, 0, stream,
                     adj00, (const unsigned*)scaled0, (unsigned*)h0b, 8000, 3000,
                     adj10, (const unsigned*)scaled2, (unsigned*)h2b, 6000);
  // --- 5. gh_gru stages 0+2 -> stP0b, stP1b ---
  hipLaunchKernelGGL(gh_gru2, dim3(500), blk, 0, stream,
                     h0b, g0Whhb, g0_bhh, gib + giOff[0] * 384, stP0b, 8000, 250,
                     h2b, g1Whhb, g1_bhh, gib + giOff[2] * 384, stP1b, 8000);
  // --- 6. logits stages 1+3 (bf16 out) ---
  {
    GSegs gs{};
    gs.s[0] = GSeg{stP0b, L01Wb, L01b, nullptr, lg1b, 8000, 1500, 0,    63};
    gs.s[1] = GSeg{stP1b, L11Wb, L11b, nullptr, lg3b, 8000, 1500, 1512, 63};
    gs.nseg = 2;
    hipLaunchKernelGGL(gemm_bf16_gseg, dim3(3024), blk, 0, stream, gs);
  }
  // --- 7. rowops stages 1+3 (paired; clsP read once) ---
  hipLaunchKernelGGL(rowops_pairb, dim3((8000 * 64 + 255) / 256), blk, 0, stream,
                     (const unsigned*)lg1b, (const unsigned*)lg3b, clsP,
                     (const unsigned*)stP0b, (const unsigned*)stP1b,
                     (unsigned*)scaled1, (unsigned*)scaled3,
                     cebuf + 1 * 8000, cebuf + 3 * 8000, 8000);
  // --- 8. spmv stages 1+3 ---
  hipLaunchKernelGGL(spmv_scan2, dim3(9000), blk, 0, stream,
                     adj01, (const unsigned*)scaled1, (unsigned*)h1b, 6000, 8000,
                     adj11, (const unsigned*)scaled3, (unsigned*)h3b, 8000);
  // --- 9. gh_gru stages 1+3 -> stA0b, stV1b ---
  hipLaunchKernelGGL(gh_gru2, dim3(188 + 94), blk, 0, stream,
                     h1b, g0Whhb, g0_bhh, gib + giOff[1] * 384, stA0b, 6000, 188,
                     h3b, g1Whhb, g1_bhh, gib + giOff[3] * 384, stV1b, 3000);
  // --- 10-13. stage 4 ---
  {
    GSegs gs{};
    gs.s[0] = GSeg{stV1b, L12Wb, L12b, nullptr, lg1b, 3000, 1500, 0, 24};
    gs.nseg = 1;
    hipLaunchKernelGGL(gemm_bf16_gseg, dim3(24 * 24), blk, 0, stream, gs);
  }
  hipLaunchKernelGGL(rowops1b, dim3((3000 * 64 + 255) / 256), blk, 0, stream,
                     (const unsigned*)lg1b, clsV, (const unsigned*)stV1b,
                     (unsigned*)scaled4, cebuf + 4 * 8000, 3000);
  hipLaunchKernelGGL(spmv_scan, dim3(1500), blk, 0, stream,
                     adj12, (const unsigned*)scaled4, (unsigned*)h4b, 1500, 3000);
  hipLaunchKernelGGL(gh_gru, dim3(47), blk, 0, stream,
                     h4b, g1Whhb, g1_bhh, gib + giOff[4] * 384, stC1b, 1500);

  // --- 14-16. fuse pipeline (bf16 e0/e1) ---
  hipLaunchKernelGGL(fuse_scores_all, dim3((18500 + 3) / 4), blk, 0, stream,
                     (const unsigned*)selfbB, (const unsigned*)stcatb, W2, b2, W3, b3, s0b, s1b);
  hipLaunchKernelGGL(denom4, dim3(4), dim3(1024), 0, stream, s0b, s1b, den);
  hipLaunchKernelGGL(fuse_emb_all, dim3((18500 * 64 + 768 + 255) / 256), blk, 0, stream,
                     (const unsigned*)selfbB, (const unsigned*)stcatb, s0b, s1b, den, rel_emb, fe, feb, rel_out);

  // --- 17. edges ---
  hipLaunchKernelGGL(edge_both, dim3(2048), blk, 0, stream, u_d, u_s, feb, relb, partial, 150000);

  // --- 18. final ---
  hipLaunchKernelGGL(final_reduce, dim3(1), dim3(1024), 0, stream, partial, cebuf, out);
}